// Round 1
// baseline (743.890 us; speedup 1.0000x reference)
//
#include <hip/hip_runtime.h>
#include <hip/hip_bf16.h>

// Problem dims
#define T_DIM 512
#define B_DIM 32
#define IN_DIM 256
#define H_DIM 256
#define K_DIM 10
#define TB 16384          // T*B
#define NKH 2560          // H*K
#define NS_ITERS 7

__device__ __forceinline__ float wave_sum64(float v) {
    #pragma unroll
    for (int off = 32; off > 0; off >>= 1) v += __shfl_xor(v, off, 64);
    return v;
}

// ---------------- weight normalize: wn[h*10+k][i], wnr[(k*256+h)][i] ----------------
__global__ __launch_bounds__(256) void wnorm_kernel(const float* __restrict__ w,
        float* __restrict__ wn, float* __restrict__ wnr) {
    int wv = threadIdx.x >> 6, lane = threadIdx.x & 63;
    int row = blockIdx.x * 4 + wv;                     // 0..2559
    const float* src = w + (size_t)row * IN_DIM;
    float v[4]; float s = 0.f;
    #pragma unroll
    for (int j = 0; j < 4; ++j) { v[j] = src[lane + 64 * j]; s += v[j] * v[j]; }
    s = wave_sum64(s);
    float inv = 1.f / fmaxf(sqrtf(s), 1e-4f);
    int h = row / K_DIM, k = row % K_DIM;
    float* d1 = wn + (size_t)row * IN_DIM;
    float* d2 = wnr + (size_t)(k * H_DIM + h) * IN_DIM;
    #pragma unroll
    for (int j = 0; j < 4; ++j) { float t = v[j] * inv; d1[lane + 64 * j] = t; d2[lane + 64 * j] = t; }
}

// ---------------- x row norms ----------------
__global__ __launch_bounds__(256) void xnorm_kernel(const float* __restrict__ x,
        float* __restrict__ xn) {
    int wv = threadIdx.x >> 6, lane = threadIdx.x & 63;
    int row = blockIdx.x * 4 + wv;                     // 0..16383
    const float* src = x + (size_t)row * IN_DIM;
    float s = 0.f;
    #pragma unroll
    for (int j = 0; j < 4; ++j) { float t = src[lane + 64 * j]; s += t * t; }
    s = wave_sum64(s);
    if (lane == 0) xn[row] = sqrtf(s);
}

// ---------------- big GEMM + kappa epilogue -> bmat bf16 [t][b][k][h] ----------------
__global__ __launch_bounds__(256) void gemm_b_kernel(const float* __restrict__ x,
        const float* __restrict__ wnr, const float* __restrict__ xn,
        __hip_bfloat16* __restrict__ bmat) {
    __shared__ float As[16][64], Bs[16][64];
    int m0 = blockIdx.x * 64, n0 = blockIdx.y * 64;    // n' = k*256+h
    int tx = threadIdx.x & 15, ty = threadIdx.x >> 4;
    int lr = threadIdx.x >> 2, lc = (threadIdx.x & 3) * 4;
    float acc[4][4] = {};
    for (int kb = 0; kb < IN_DIM; kb += 16) {
        float4 a4 = *(const float4*)(x   + (size_t)(m0 + lr) * IN_DIM + kb + lc);
        float4 b4 = *(const float4*)(wnr + (size_t)(n0 + lr) * IN_DIM + kb + lc);
        __syncthreads();
        As[lc+0][lr]=a4.x; As[lc+1][lr]=a4.y; As[lc+2][lr]=a4.z; As[lc+3][lr]=a4.w;
        Bs[lc+0][lr]=b4.x; Bs[lc+1][lr]=b4.y; Bs[lc+2][lr]=b4.z; Bs[lc+3][lr]=b4.w;
        __syncthreads();
        #pragma unroll
        for (int kc = 0; kc < 16; ++kc) {
            float a_[4], b_[4];
            #pragma unroll
            for (int i = 0; i < 4; ++i) a_[i] = As[kc][ty * 4 + i];
            #pragma unroll
            for (int j = 0; j < 4; ++j) b_[j] = Bs[kc][tx * 4 + j];
            #pragma unroll
            for (int i = 0; i < 4; ++i)
                #pragma unroll
                for (int j = 0; j < 4; ++j) acc[i][j] = fmaf(a_[i], b_[j], acc[i][j]);
        }
    }
    int kk = n0 >> 8;
    int h0 = (n0 & 255) + tx * 4;
    #pragma unroll
    for (int i = 0; i < 4; ++i) {
        int m = m0 + ty * 4 + i;
        float nrm = xn[m];
        float dn = fmaxf(nrm, 1e-4f);
        __hip_bfloat16* dst = bmat + ((size_t)m * K_DIM + kk) * H_DIM + h0;
        #pragma unroll
        for (int j = 0; j < 4; ++j) {
            float bv = nrm * __expf(0.4f * (acc[i][j] / dn) - 0.4f);
            dst[j] = __float2bfloat16(bv);
        }
    }
}

// ---------------- recurrence with warm-up chunks ----------------
// grid 256 blocks: blockIdx = s*32+b (8 chunks of 64 output steps, 64-step warm-up)
__global__ __launch_bounds__(256) void rec_kernel(const __hip_bfloat16* __restrict__ bmat,
        float* __restrict__ cs9, float* __restrict__ part, float* __restrict__ hxT) {
    int s = blockIdx.x >> 5;
    int b = blockIdx.x & 31;
    int h = threadIdx.x;
    int tout0 = s * 64;
    int t0 = (s == 0) ? 0 : tout0 - 64;
    int t1 = tout0 + 64;
    float c[10] = {};
    float s9 = 0.f;
    float bt[10];
    {
        const __hip_bfloat16* bp = bmat + ((size_t)(t0 * B_DIM + b) * K_DIM) * H_DIM + h;
        #pragma unroll
        for (int k = 0; k < 10; ++k) bt[k] = __bfloat162float(bp[k * H_DIM]);
    }
    for (int t = t0; t < t1; ++t) {
        int tn = (t + 1 < t1) ? t + 1 : t;
        float btn[10];
        const __hip_bfloat16* bq = bmat + ((size_t)(tn * B_DIM + b) * K_DIM) * H_DIM + h;
        #pragma unroll
        for (int k = 0; k < 10; ++k) btn[k] = __bfloat162float(bq[k * H_DIM]);
        #pragma unroll
        for (int j = 9; j >= 1; --j) c[j] = 0.5f * c[j] + c[j - 1] * bt[j];
        c[0] = 0.5f * c[0] + bt[0];
        if (t >= tout0) {
            cs9[(size_t)(t * B_DIM + b) * H_DIM + h] = c[9];
            s9 += c[9];
        }
        #pragma unroll
        for (int k = 0; k < 10; ++k) bt[k] = btn[k];
    }
    part[(size_t)(s * B_DIM + b) * H_DIM + h] = s9;
    if (s == 7) {
        float* hp = hxT + (size_t)(b * H_DIM + h) * K_DIM;
        #pragma unroll
        for (int k = 0; k < 10; ++k) hp[k] = c[k];
    }
}

__global__ __launch_bounds__(256) void recred_kernel(const float* __restrict__ part,
        float* __restrict__ mean9) {
    int i = blockIdx.x * 256 + threadIdx.x;            // 0..8191
    float s = 0.f;
    #pragma unroll
    for (int j = 0; j < 8; ++j) s += part[(size_t)j * 8192 + i];
    mean9[i] = s * (1.f / T_DIM);
}

// ---------------- Gram product: M[h][g] = exp(0.4*sum_k <wn_hk, wn_gk> - 4) ----------------
__global__ __launch_bounds__(256) void gram_kernel(const float* __restrict__ wn,
        float* __restrict__ Mo) {
    __shared__ float As[32][33], Bs[32][33];
    int h0 = blockIdx.x * 32, g0 = blockIdx.y * 32;
    int tx = threadIdx.x & 15, ty = threadIdx.x >> 4;
    int lr = threadIdx.x >> 3;          // 0..31
    int lc = (threadIdx.x & 7) * 4;     // 0..28
    float acc[2][2] = {};
    for (int kb = 0; kb < NKH; kb += 32) {
        float4 a = *(const float4*)(wn + (size_t)(h0 + lr) * NKH + kb + lc);
        float4 b = *(const float4*)(wn + (size_t)(g0 + lr) * NKH + kb + lc);
        __syncthreads();
        As[lc+0][lr]=a.x; As[lc+1][lr]=a.y; As[lc+2][lr]=a.z; As[lc+3][lr]=a.w;
        Bs[lc+0][lr]=b.x; Bs[lc+1][lr]=b.y; Bs[lc+2][lr]=b.z; Bs[lc+3][lr]=b.w;
        __syncthreads();
        #pragma unroll
        for (int kc = 0; kc < 32; ++kc) {
            float a0 = As[kc][ty*2+0], a1 = As[kc][ty*2+1];
            float b0 = Bs[kc][tx*2+0], b1 = Bs[kc][tx*2+1];
            acc[0][0]=fmaf(a0,b0,acc[0][0]); acc[0][1]=fmaf(a0,b1,acc[0][1]);
            acc[1][0]=fmaf(a1,b0,acc[1][0]); acc[1][1]=fmaf(a1,b1,acc[1][1]);
        }
    }
    #pragma unroll
    for (int i = 0; i < 2; ++i)
        #pragma unroll
        for (int j = 0; j < 2; ++j)
            Mo[(size_t)(h0 + ty*2 + i) * H_DIM + g0 + tx*2 + j] = __expf(0.4f * acc[i][j] - 4.0f);
}

// ---------------- max row sum -> cbuf = {c, 1/c, 1/sqrt(c)} ----------------
__global__ __launch_bounds__(256) void rowmax_kernel(const float* __restrict__ M,
        float* __restrict__ cbuf) {
    int h = threadIdx.x;
    float s = 0.f;
    for (int g = 0; g < H_DIM; ++g) s += M[(size_t)h * H_DIM + g];
    __shared__ float red[256];
    red[h] = s; __syncthreads();
    for (int st = 128; st > 0; st >>= 1) {
        if (h < st) red[h] = fmaxf(red[h], red[h + st]);
        __syncthreads();
    }
    if (h == 0) { float c = red[0]; cbuf[0] = c; cbuf[1] = 1.f / c; cbuf[2] = rsqrtf(c); }
}

__global__ __launch_bounds__(256) void nsinit_kernel(const float* __restrict__ M,
        float* __restrict__ Y, float* __restrict__ Z, const float* __restrict__ cbuf) {
    int i = blockIdx.x * 256 + threadIdx.x;
    float invc = cbuf[1];
    Y[i] = M[i] * invc;
    Z[i] = ((i >> 8) == (i & 255)) ? 1.f : 0.f;
}

// ---------------- shared 64x64 fp32 tile MM core (A: Mx256 row-major, B: 256x256 row-major) ----
__device__ __forceinline__ void mm64_core(const float* __restrict__ A, const float* __restrict__ B,
        float As[16][64], float Bs[16][64], int m0, int n0, float acc[4][4]) {
    int tx = threadIdx.x & 15, ty = threadIdx.x >> 4;
    int lr = threadIdx.x >> 2, lc = (threadIdx.x & 3) * 4;
    int cb = threadIdx.x >> 6, jb = threadIdx.x & 63;
    for (int kb = 0; kb < 256; kb += 16) {
        float4 a4 = *(const float4*)(A + (size_t)(m0 + lr) * 256 + kb + lc);
        float b0 = B[(size_t)(kb + cb +  0) * 256 + n0 + jb];
        float b1 = B[(size_t)(kb + cb +  4) * 256 + n0 + jb];
        float b2 = B[(size_t)(kb + cb +  8) * 256 + n0 + jb];
        float b3 = B[(size_t)(kb + cb + 12) * 256 + n0 + jb];
        __syncthreads();
        As[lc+0][lr]=a4.x; As[lc+1][lr]=a4.y; As[lc+2][lr]=a4.z; As[lc+3][lr]=a4.w;
        Bs[cb][jb]=b0; Bs[cb+4][jb]=b1; Bs[cb+8][jb]=b2; Bs[cb+12][jb]=b3;
        __syncthreads();
        #pragma unroll
        for (int kc = 0; kc < 16; ++kc) {
            float a_[4], b_[4];
            #pragma unroll
            for (int i = 0; i < 4; ++i) a_[i] = As[kc][ty * 4 + i];
            #pragma unroll
            for (int j = 0; j < 4; ++j) b_[j] = Bs[kc][tx * 4 + j];
            #pragma unroll
            for (int i = 0; i < 4; ++i)
                #pragma unroll
                for (int j = 0; j < 4; ++j) acc[i][j] = fmaf(a_[i], b_[j], acc[i][j]);
        }
    }
}

// mode 0: C = 3I - A@B ; mode 1: C = 0.5*A@B ; mode 2: C = (A@B)*cbuf[2]
__global__ __launch_bounds__(256) void mm_mode_kernel(const float* __restrict__ A,
        const float* __restrict__ B, float* __restrict__ C, int mode,
        const float* __restrict__ cbuf) {
    __shared__ float As[16][64], Bs[16][64];
    int m0 = blockIdx.x * 64, n0 = blockIdx.y * 64;
    float acc[4][4] = {};
    mm64_core(A, B, As, Bs, m0, n0, acc);
    int tx = threadIdx.x & 15, ty = threadIdx.x >> 4;
    float scale = (mode == 2) ? cbuf[2] : 1.0f;
    #pragma unroll
    for (int i = 0; i < 4; ++i) {
        int m = m0 + ty * 4 + i;
        float* crow = C + (size_t)m * 256 + n0 + tx * 4;
        #pragma unroll
        for (int j = 0; j < 4; ++j) {
            int n = n0 + tx * 4 + j;
            float v = acc[i][j];
            if (mode == 0)      v = ((m == n) ? 3.0f : 0.0f) - v;
            else if (mode == 1) v = 0.5f * v;
            else                v = v * scale;
            crow[j] = v;
        }
    }
}

// fused NS second step: z=0 -> Yn = 0.5*Y@W ; z=1 -> Zn = 0.5*W@Z
__global__ __launch_bounds__(256) void nsB_kernel(const float* __restrict__ Y,
        const float* __restrict__ Z, const float* __restrict__ W,
        float* __restrict__ Yn, float* __restrict__ Zn) {
    __shared__ float As[16][64], Bs[16][64];
    const float *A, *B; float* C;
    if (blockIdx.z == 0) { A = Y; B = W; C = Yn; }
    else                 { A = W; B = Z; C = Zn; }
    int m0 = blockIdx.x * 64, n0 = blockIdx.y * 64;
    float acc[4][4] = {};
    mm64_core(A, B, As, Bs, m0, n0, acc);
    int tx = threadIdx.x & 15, ty = threadIdx.x >> 4;
    #pragma unroll
    for (int i = 0; i < 4; ++i) {
        float* crow = C + (size_t)(m0 + ty * 4 + i) * 256 + n0 + tx * 4;
        #pragma unroll
        for (int j = 0; j < 4; ++j) crow[j] = 0.5f * acc[i][j];
    }
}

// output[b][g] = sum_h mean9[b][h]*lin[h][g]*s
__global__ __launch_bounds__(256) void outmean_kernel(const float* __restrict__ mean9,
        const float* __restrict__ lin, const float* __restrict__ cbuf,
        float* __restrict__ out) {
    int b = blockIdx.x, g = threadIdx.x;
    float s = cbuf[2];
    float acc = 0.f;
    for (int h = 0; h < H_DIM; ++h) acc = fmaf(mean9[b * H_DIM + h], lin[(size_t)h * H_DIM + g], acc);
    out[b * H_DIM + g] = acc * s;
}

extern "C" void kernel_launch(void* const* d_in, const int* in_sizes, int n_in,
                              void* d_out, int out_size, void* d_ws, size_t ws_size,
                              hipStream_t stream) {
    const float* x = (const float*)d_in[0];
    const float* w = (const float*)d_in[1];
    float* out0 = (float*)d_out;                       // B*H
    float* out1 = out0 + (size_t)B_DIM * H_DIM;        // T*B*H
    float* hxT  = out1 + (size_t)TB * H_DIM;           // B*H*K

    char* ws = (char*)d_ws;
    float* wn    = (float*)(ws + 0);                   // 2,621,440
    float* wnr   = (float*)(ws + 2621440);             // 2,621,440
    float* xn    = (float*)(ws + 5242880);             //    65,536
    float* Mm    = (float*)(ws + 5308416);             //   262,144
    float* Y0    = (float*)(ws + 5570560);             //   262,144
    float* Z0    = (float*)(ws + 5832704);             //   262,144
    float* Y1    = (float*)(ws + 6094848);             //   262,144
    float* Z1    = (float*)(ws + 6356992);             //   262,144
    float* Wb    = (float*)(ws + 6619136);             //   262,144
    float* cbuf  = (float*)(ws + 6881280);             //     1,024
    float* mean9 = (float*)(ws + 6882304);             //    32,768
    float* part  = (float*)(ws + 6915072);             //   262,144
    float* cs9   = (float*)(ws + 7177216);             // 16,777,216
    __hip_bfloat16* bmat = (__hip_bfloat16*)(ws + 23954432); // 83,886,080 -> total ~103 MB

    wnorm_kernel<<<dim3(640), dim3(256), 0, stream>>>(w, wn, wnr);
    xnorm_kernel<<<dim3(4096), dim3(256), 0, stream>>>(x, xn);
    gemm_b_kernel<<<dim3(256, 40), dim3(256), 0, stream>>>(x, wnr, xn, bmat);
    rec_kernel<<<dim3(256), dim3(256), 0, stream>>>(bmat, cs9, part, hxT);
    recred_kernel<<<dim3(32), dim3(256), 0, stream>>>(part, mean9);
    gram_kernel<<<dim3(8, 8), dim3(256), 0, stream>>>(wn, Mm);
    rowmax_kernel<<<dim3(1), dim3(256), 0, stream>>>(Mm, cbuf);
    nsinit_kernel<<<dim3(256), dim3(256), 0, stream>>>(Mm, Y0, Z0, cbuf);
    float *Yc = Y0, *Zc = Z0, *Yn = Y1, *Zn = Z1;
    for (int it = 0; it < NS_ITERS; ++it) {
        mm_mode_kernel<<<dim3(4, 4), dim3(256), 0, stream>>>(Zc, Yc, Wb, 0, cbuf);
        nsB_kernel<<<dim3(4, 4, 2), dim3(256), 0, stream>>>(Yc, Zc, Wb, Yn, Zn);
        float* t;
        t = Yc; Yc = Yn; Yn = t;
        t = Zc; Zc = Zn; Zn = t;
    }
    // outputs = cs9 @ lin * (1/sqrt(c)) ; lin = Zc
    mm_mode_kernel<<<dim3(256, 4), dim3(256), 0, stream>>>(cs9, Zc, out1, 2, cbuf);
    outmean_kernel<<<dim3(32), dim3(256), 0, stream>>>(mean9, Zc, cbuf, out0);
}

// Round 2
// 492.958 us; speedup vs baseline: 1.5090x; 1.5090x over previous
//
#include <hip/hip_runtime.h>
#include <hip/hip_bf16.h>

// Problem dims
#define T_DIM 512
#define B_DIM 32
#define IN_DIM 256
#define H_DIM 256
#define K_DIM 10
#define TB 16384          // T*B
#define NKH 2560          // H*K
#define NS_ITERS 7

typedef __attribute__((ext_vector_type(8))) short short8;
typedef __attribute__((ext_vector_type(4))) float f32x4;

#define GLOBAL_AS __attribute__((address_space(1)))
#define LDS_AS __attribute__((address_space(3)))

__device__ __forceinline__ float wave_sum64(float v) {
    #pragma unroll
    for (int off = 32; off > 0; off >>= 1) v += __shfl_xor(v, off, 64);
    return v;
}

// ---------------- weight normalize: wn fp32 [h*10+k][i] (for gram), wb bf16 [(k*256+h)][i] ----
__global__ __launch_bounds__(256) void wnorm_kernel(const float* __restrict__ w,
        float* __restrict__ wn, __hip_bfloat16* __restrict__ wb) {
    int wv = threadIdx.x >> 6, lane = threadIdx.x & 63;
    int row = blockIdx.x * 4 + wv;                     // 0..2559
    const float* src = w + (size_t)row * IN_DIM;
    float v[4]; float s = 0.f;
    #pragma unroll
    for (int j = 0; j < 4; ++j) { v[j] = src[lane + 64 * j]; s += v[j] * v[j]; }
    s = wave_sum64(s);
    float inv = 1.f / fmaxf(sqrtf(s), 1e-4f);
    int h = row / K_DIM, k = row % K_DIM;
    float* d1 = wn + (size_t)row * IN_DIM;
    __hip_bfloat16* d2 = wb + (size_t)(k * H_DIM + h) * IN_DIM;
    #pragma unroll
    for (int j = 0; j < 4; ++j) {
        float t = v[j] * inv;
        d1[lane + 64 * j] = t;
        d2[lane + 64 * j] = __float2bfloat16(t);
    }
}

// ---------------- x row norms + bf16 copy ----------------
// xninfo[2*row] = norm, xninfo[2*row+1] = 1/max(norm,1e-4)
__global__ __launch_bounds__(256) void xnorm_kernel(const float* __restrict__ x,
        float* __restrict__ xninfo, __hip_bfloat16* __restrict__ xb) {
    int wv = threadIdx.x >> 6, lane = threadIdx.x & 63;
    int row = blockIdx.x * 4 + wv;                     // 0..16383
    const float* src = x + (size_t)row * IN_DIM;
    float v[4]; float s = 0.f;
    #pragma unroll
    for (int j = 0; j < 4; ++j) { v[j] = src[lane + 64 * j]; s += v[j] * v[j]; }
    s = wave_sum64(s);
    float nrm = sqrtf(s);
    if (lane == 0) { xninfo[2 * row] = nrm; xninfo[2 * row + 1] = 1.f / fmaxf(nrm, 1e-4f); }
    __hip_bfloat16* d = xb + (size_t)row * IN_DIM;
    #pragma unroll
    for (int j = 0; j < 4; ++j) d[lane + 64 * j] = __float2bfloat16(v[j]);
}

// ---------------- big GEMM via bf16 MFMA + kappa epilogue -> bmat bf16 [t][b][k][h] ----------
// A = xb [16384][256] bf16 row-major; B = wb [2560][256] bf16 row-major (B^T form).
// Tile 128x128, BK=32, 4 waves in 2x2, each wave 64x64 via 4x4 frags of 16x16x32.
__global__ __launch_bounds__(256) void gemm_b_mfma(const __hip_bfloat16* __restrict__ xb,
        const __hip_bfloat16* __restrict__ wb, const float* __restrict__ xninfo,
        __hip_bfloat16* __restrict__ bmat) {
    __shared__ __hip_bfloat16 As[4096];   // [128][32]
    __shared__ __hip_bfloat16 Bs[4096];
    int tid = threadIdx.x;
    int wid = tid >> 6, lane = tid & 63;
    int m0 = blockIdx.x * 128, n0 = blockIdx.y * 128;
    int wr = wid >> 1, wc = wid & 1;
    int srow = tid >> 2;                 // 0..63 staging row within half
    int scol = (tid & 3) * 8;            // staging k element
    f32x4 acc[4][4] = {};

    for (int kb = 0; kb < IN_DIM; kb += 32) {
        // stage A and B tiles: 2 halves x 64 rows, 16B per lane, linear LDS
        #pragma unroll
        for (int half = 0; half < 2; ++half) {
            const __hip_bfloat16* ga = xb + (size_t)(m0 + half * 64 + srow) * IN_DIM + kb + scol;
            const __hip_bfloat16* gb = wb + (size_t)(n0 + half * 64 + srow) * IN_DIM + kb + scol;
            __builtin_amdgcn_global_load_lds((const GLOBAL_AS void*)ga,
                (LDS_AS void*)(As + half * 2048 + wid * 512), 16, 0, 0);
            __builtin_amdgcn_global_load_lds((const GLOBAL_AS void*)gb,
                (LDS_AS void*)(Bs + half * 2048 + wid * 512), 16, 0, 0);
        }
        __syncthreads();   // drains vmcnt(0) before barrier -> LDS ready
        int seg = (lane >> 4) * 8;
        int rl = lane & 15;
        short8 a[4], b[4];
        #pragma unroll
        for (int m = 0; m < 4; ++m)
            a[m] = *(const short8*)(As + (wr * 64 + m * 16 + rl) * 32 + seg);
        #pragma unroll
        for (int n = 0; n < 4; ++n)
            b[n] = *(const short8*)(Bs + (wc * 64 + n * 16 + rl) * 32 + seg);
        #pragma unroll
        for (int m = 0; m < 4; ++m)
            #pragma unroll
            for (int n = 0; n < 4; ++n)
                acc[m][n] = __builtin_amdgcn_mfma_f32_16x16x32_bf16(a[m], b[n], acc[m][n], 0, 0, 0);
        __syncthreads();   // all waves done reading before next stage
    }

    // epilogue: C row = (lane>>4)*4 + j, col = lane&15 within each 16x16 frag
    int kk = blockIdx.y >> 1;            // n0>>8, constant per block
    int col_l = lane & 15;
    int rseg = (lane >> 4) * 4;
    #pragma unroll
    for (int m = 0; m < 4; ++m) {
        int rbase = m0 + wr * 64 + m * 16 + rseg;     // 4 consecutive rows
        float4 q0 = *(const float4*)(xninfo + 2 * rbase);
        float4 q1 = *(const float4*)(xninfo + 2 * rbase + 4);
        float nrm[4] = { q0.x, q0.z, q1.x, q1.z };
        float inv[4] = { q0.y, q0.w, q1.y, q1.w };
        #pragma unroll
        for (int n = 0; n < 4; ++n) {
            int col = n0 + wc * 64 + n * 16 + col_l;
            int h = col & 255;
            #pragma unroll
            for (int j = 0; j < 4; ++j) {
                float bv = nrm[j] * __expf(0.4f * acc[m][n][j] * inv[j] - 0.4f);
                bmat[((size_t)(rbase + j) * K_DIM + kk) * H_DIM + h] = __float2bfloat16(bv);
            }
        }
    }
}

// ---------------- recurrence with warm-up chunks ----------------
__global__ __launch_bounds__(256) void rec_kernel(const __hip_bfloat16* __restrict__ bmat,
        float* __restrict__ cs9, float* __restrict__ part, float* __restrict__ hxT) {
    int s = blockIdx.x >> 5;
    int b = blockIdx.x & 31;
    int h = threadIdx.x;
    int tout0 = s * 64;
    int t0 = (s == 0) ? 0 : tout0 - 64;
    int t1 = tout0 + 64;
    float c[10] = {};
    float s9 = 0.f;
    float bt[10];
    {
        const __hip_bfloat16* bp = bmat + ((size_t)(t0 * B_DIM + b) * K_DIM) * H_DIM + h;
        #pragma unroll
        for (int k = 0; k < 10; ++k) bt[k] = __bfloat162float(bp[k * H_DIM]);
    }
    for (int t = t0; t < t1; ++t) {
        int tn = (t + 1 < t1) ? t + 1 : t;
        float btn[10];
        const __hip_bfloat16* bq = bmat + ((size_t)(tn * B_DIM + b) * K_DIM) * H_DIM + h;
        #pragma unroll
        for (int k = 0; k < 10; ++k) btn[k] = __bfloat162float(bq[k * H_DIM]);
        #pragma unroll
        for (int j = 9; j >= 1; --j) c[j] = 0.5f * c[j] + c[j - 1] * bt[j];
        c[0] = 0.5f * c[0] + bt[0];
        if (t >= tout0) {
            cs9[(size_t)(t * B_DIM + b) * H_DIM + h] = c[9];
            s9 += c[9];
        }
        #pragma unroll
        for (int k = 0; k < 10; ++k) bt[k] = btn[k];
    }
    part[(size_t)(s * B_DIM + b) * H_DIM + h] = s9;
    if (s == 7) {
        float* hp = hxT + (size_t)(b * H_DIM + h) * K_DIM;
        #pragma unroll
        for (int k = 0; k < 10; ++k) hp[k] = c[k];
    }
}

__global__ __launch_bounds__(256) void recred_kernel(const float* __restrict__ part,
        float* __restrict__ mean9) {
    int i = blockIdx.x * 256 + threadIdx.x;            // 0..8191
    float s = 0.f;
    #pragma unroll
    for (int j = 0; j < 8; ++j) s += part[(size_t)j * 8192 + i];
    mean9[i] = s * (1.f / T_DIM);
}

// ---------------- Gram product: M[h][g] = exp(0.4*sum_k <wn_hk, wn_gk> - 4) ----------------
__global__ __launch_bounds__(256) void gram_kernel(const float* __restrict__ wn,
        float* __restrict__ Mo) {
    __shared__ float As[32][33], Bs[32][33];
    int h0 = blockIdx.x * 32, g0 = blockIdx.y * 32;
    int tx = threadIdx.x & 15, ty = threadIdx.x >> 4;
    int lr = threadIdx.x >> 3;          // 0..31
    int lc = (threadIdx.x & 7) * 4;     // 0..28
    float acc[2][2] = {};
    for (int kb = 0; kb < NKH; kb += 32) {
        float4 a = *(const float4*)(wn + (size_t)(h0 + lr) * NKH + kb + lc);
        float4 b = *(const float4*)(wn + (size_t)(g0 + lr) * NKH + kb + lc);
        __syncthreads();
        As[lc+0][lr]=a.x; As[lc+1][lr]=a.y; As[lc+2][lr]=a.z; As[lc+3][lr]=a.w;
        Bs[lc+0][lr]=b.x; Bs[lc+1][lr]=b.y; Bs[lc+2][lr]=b.z; Bs[lc+3][lr]=b.w;
        __syncthreads();
        #pragma unroll
        for (int kc = 0; kc < 32; ++kc) {
            float a0 = As[kc][ty*2+0], a1 = As[kc][ty*2+1];
            float b0 = Bs[kc][tx*2+0], b1 = Bs[kc][tx*2+1];
            acc[0][0]=fmaf(a0,b0,acc[0][0]); acc[0][1]=fmaf(a0,b1,acc[0][1]);
            acc[1][0]=fmaf(a1,b0,acc[1][0]); acc[1][1]=fmaf(a1,b1,acc[1][1]);
        }
    }
    #pragma unroll
    for (int i = 0; i < 2; ++i)
        #pragma unroll
        for (int j = 0; j < 2; ++j)
            Mo[(size_t)(h0 + ty*2 + i) * H_DIM + g0 + tx*2 + j] = __expf(0.4f * acc[i][j] - 4.0f);
}

// ---------------- max row sum -> cbuf = {c, 1/c, 1/sqrt(c)} ----------------
__global__ __launch_bounds__(256) void rowmax_kernel(const float* __restrict__ M,
        float* __restrict__ cbuf) {
    int h = threadIdx.x;
    float s = 0.f;
    for (int g = 0; g < H_DIM; ++g) s += M[(size_t)h * H_DIM + g];
    __shared__ float red[256];
    red[h] = s; __syncthreads();
    for (int st = 128; st > 0; st >>= 1) {
        if (h < st) red[h] = fmaxf(red[h], red[h + st]);
        __syncthreads();
    }
    if (h == 0) { float c = red[0]; cbuf[0] = c; cbuf[1] = 1.f / c; cbuf[2] = rsqrtf(c); }
}

__global__ __launch_bounds__(256) void nsinit_kernel(const float* __restrict__ M,
        float* __restrict__ Y, float* __restrict__ Z, const float* __restrict__ cbuf) {
    int i = blockIdx.x * 256 + threadIdx.x;
    float invc = cbuf[1];
    Y[i] = M[i] * invc;
    Z[i] = ((i >> 8) == (i & 255)) ? 1.f : 0.f;
}

// ---------------- shared 64x64 fp32 tile MM core (A: Mx256 row-major, B: 256x256 row-major) ----
__device__ __forceinline__ void mm64_core(const float* __restrict__ A, const float* __restrict__ B,
        float As[16][64], float Bs[16][64], int m0, int n0, float acc[4][4]) {
    int tx = threadIdx.x & 15, ty = threadIdx.x >> 4;
    int lr = threadIdx.x >> 2, lc = (threadIdx.x & 3) * 4;
    int cb = threadIdx.x >> 6, jb = threadIdx.x & 63;
    for (int kb = 0; kb < 256; kb += 16) {
        float4 a4 = *(const float4*)(A + (size_t)(m0 + lr) * 256 + kb + lc);
        float b0 = B[(size_t)(kb + cb +  0) * 256 + n0 + jb];
        float b1 = B[(size_t)(kb + cb +  4) * 256 + n0 + jb];
        float b2 = B[(size_t)(kb + cb +  8) * 256 + n0 + jb];
        float b3 = B[(size_t)(kb + cb + 12) * 256 + n0 + jb];
        __syncthreads();
        As[lc+0][lr]=a4.x; As[lc+1][lr]=a4.y; As[lc+2][lr]=a4.z; As[lc+3][lr]=a4.w;
        Bs[cb][jb]=b0; Bs[cb+4][jb]=b1; Bs[cb+8][jb]=b2; Bs[cb+12][jb]=b3;
        __syncthreads();
        #pragma unroll
        for (int kc = 0; kc < 16; ++kc) {
            float a_[4], b_[4];
            #pragma unroll
            for (int i = 0; i < 4; ++i) a_[i] = As[kc][ty * 4 + i];
            #pragma unroll
            for (int j = 0; j < 4; ++j) b_[j] = Bs[kc][tx * 4 + j];
            #pragma unroll
            for (int i = 0; i < 4; ++i)
                #pragma unroll
                for (int j = 0; j < 4; ++j) acc[i][j] = fmaf(a_[i], b_[j], acc[i][j]);
        }
    }
}

// mode 0: C = 3I - A@B ; mode 1: C = 0.5*A@B ; mode 2: C = (A@B)*cbuf[2]
__global__ __launch_bounds__(256) void mm_mode_kernel(const float* __restrict__ A,
        const float* __restrict__ B, float* __restrict__ C, int mode,
        const float* __restrict__ cbuf) {
    __shared__ float As[16][64], Bs[16][64];
    int m0 = blockIdx.x * 64, n0 = blockIdx.y * 64;
    float acc[4][4] = {};
    mm64_core(A, B, As, Bs, m0, n0, acc);
    int tx = threadIdx.x & 15, ty = threadIdx.x >> 4;
    float scale = (mode == 2) ? cbuf[2] : 1.0f;
    #pragma unroll
    for (int i = 0; i < 4; ++i) {
        int m = m0 + ty * 4 + i;
        float* crow = C + (size_t)m * 256 + n0 + tx * 4;
        #pragma unroll
        for (int j = 0; j < 4; ++j) {
            int n = n0 + tx * 4 + j;
            float v = acc[i][j];
            if (mode == 0)      v = ((m == n) ? 3.0f : 0.0f) - v;
            else if (mode == 1) v = 0.5f * v;
            else                v = v * scale;
            crow[j] = v;
        }
    }
}

// fused NS second step: z=0 -> Yn = 0.5*Y@W ; z=1 -> Zn = 0.5*W@Z
__global__ __launch_bounds__(256) void nsB_kernel(const float* __restrict__ Y,
        const float* __restrict__ Z, const float* __restrict__ W,
        float* __restrict__ Yn, float* __restrict__ Zn) {
    __shared__ float As[16][64], Bs[16][64];
    const float *A, *B; float* C;
    if (blockIdx.z == 0) { A = Y; B = W; C = Yn; }
    else                 { A = W; B = Z; C = Zn; }
    int m0 = blockIdx.x * 64, n0 = blockIdx.y * 64;
    float acc[4][4] = {};
    mm64_core(A, B, As, Bs, m0, n0, acc);
    int tx = threadIdx.x & 15, ty = threadIdx.x >> 4;
    #pragma unroll
    for (int i = 0; i < 4; ++i) {
        float* crow = C + (size_t)(m0 + ty * 4 + i) * 256 + n0 + tx * 4;
        #pragma unroll
        for (int j = 0; j < 4; ++j) crow[j] = 0.5f * acc[i][j];
    }
}

// output[b][g] = sum_h mean9[b][h]*lin[h][g]*s
__global__ __launch_bounds__(256) void outmean_kernel(const float* __restrict__ mean9,
        const float* __restrict__ lin, const float* __restrict__ cbuf,
        float* __restrict__ out) {
    int b = blockIdx.x, g = threadIdx.x;
    float s = cbuf[2];
    float acc = 0.f;
    for (int h = 0; h < H_DIM; ++h) acc = fmaf(mean9[b * H_DIM + h], lin[(size_t)h * H_DIM + g], acc);
    out[b * H_DIM + g] = acc * s;
}

extern "C" void kernel_launch(void* const* d_in, const int* in_sizes, int n_in,
                              void* d_out, int out_size, void* d_ws, size_t ws_size,
                              hipStream_t stream) {
    const float* x = (const float*)d_in[0];
    const float* w = (const float*)d_in[1];
    float* out0 = (float*)d_out;                       // B*H
    float* out1 = out0 + (size_t)B_DIM * H_DIM;        // T*B*H
    float* hxT  = out1 + (size_t)TB * H_DIM;           // B*H*K

    char* ws = (char*)d_ws;
    float* wn            = (float*)(ws + 0);              // 2,621,440
    __hip_bfloat16* wb   = (__hip_bfloat16*)(ws + 2621440);   // 1,310,720
    float* xninfo        = (float*)(ws + 3932160);        //   131,072
    float* Mm            = (float*)(ws + 4063232);        //   262,144
    float* Y0            = (float*)(ws + 4325376);        //   262,144
    float* Z0            = (float*)(ws + 4587520);        //   262,144
    float* Y1            = (float*)(ws + 4849664);        //   262,144
    float* Z1            = (float*)(ws + 5111808);        //   262,144
    float* Wb            = (float*)(ws + 5373952);        //   262,144
    float* cbuf          = (float*)(ws + 5636096);        //     1,024
    float* mean9         = (float*)(ws + 5637120);        //    32,768
    float* part          = (float*)(ws + 5669888);        //   262,144
    float* cs9           = (float*)(ws + 5932032);        // 16,777,216
    __hip_bfloat16* xb   = (__hip_bfloat16*)cs9;          // aliases cs9 (dead before rec writes)
    __hip_bfloat16* bmat = (__hip_bfloat16*)(ws + 22709248); // 83,886,080 -> total ~106.6 MB

    wnorm_kernel<<<dim3(640), dim3(256), 0, stream>>>(w, wn, wb);
    xnorm_kernel<<<dim3(4096), dim3(256), 0, stream>>>(x, xninfo, xb);
    gemm_b_mfma<<<dim3(128, 20), dim3(256), 0, stream>>>(xb, wb, xninfo, bmat);
    rec_kernel<<<dim3(256), dim3(256), 0, stream>>>(bmat, cs9, part, hxT);
    recred_kernel<<<dim3(32), dim3(256), 0, stream>>>(part, mean9);
    gram_kernel<<<dim3(8, 8), dim3(256), 0, stream>>>(wn, Mm);
    rowmax_kernel<<<dim3(1), dim3(256), 0, stream>>>(Mm, cbuf);
    nsinit_kernel<<<dim3(256), dim3(256), 0, stream>>>(Mm, Y0, Z0, cbuf);
    float *Yc = Y0, *Zc = Z0, *Yn = Y1, *Zn = Z1;
    for (int it = 0; it < NS_ITERS; ++it) {
        mm_mode_kernel<<<dim3(4, 4), dim3(256), 0, stream>>>(Zc, Yc, Wb, 0, cbuf);
        nsB_kernel<<<dim3(4, 4, 2), dim3(256), 0, stream>>>(Yc, Zc, Wb, Yn, Zn);
        float* t;
        t = Yc; Yc = Yn; Yn = t;
        t = Zc; Zc = Zn; Zn = t;
    }
    // outputs = cs9 @ lin * (1/sqrt(c)) ; lin = Zc
    mm_mode_kernel<<<dim3(256, 4), dim3(256), 0, stream>>>(cs9, Zc, out1, 2, cbuf);
    outmean_kernel<<<dim3(32), dim3(256), 0, stream>>>(mean9, Zc, cbuf, out0);
}

// Round 3
// 445.333 us; speedup vs baseline: 1.6704x; 1.1069x over previous
//
#include <hip/hip_runtime.h>
#include <hip/hip_bf16.h>
#include <hip/hip_cooperative_groups.h>

namespace cg = cooperative_groups;

// Problem dims
#define T_DIM 512
#define B_DIM 32
#define IN_DIM 256
#define H_DIM 256
#define K_DIM 10
#define TB 16384          // T*B
#define NKH 2560          // H*K
#define NS_ITERS 7

typedef __attribute__((ext_vector_type(8))) short short8;
typedef __attribute__((ext_vector_type(4))) float f32x4;

#define GLOBAL_AS __attribute__((address_space(1)))
#define LDS_AS __attribute__((address_space(3)))

__device__ __forceinline__ float wave_sum64(float v) {
    #pragma unroll
    for (int off = 32; off > 0; off >>= 1) v += __shfl_xor(v, off, 64);
    return v;
}

// ---- weight normalize: wb bf16 [(k*256+h)][256] (for gemm_b), wb2 bf16 [h][k*256+i] (for gram)
__global__ __launch_bounds__(256) void wnorm_kernel(const float* __restrict__ w,
        __hip_bfloat16* __restrict__ wb, __hip_bfloat16* __restrict__ wb2) {
    int wv = threadIdx.x >> 6, lane = threadIdx.x & 63;
    int row = blockIdx.x * 4 + wv;                     // 0..2559  (= h*10+k)
    const float* src = w + (size_t)row * IN_DIM;
    float v[4]; float s = 0.f;
    #pragma unroll
    for (int j = 0; j < 4; ++j) { v[j] = src[lane + 64 * j]; s += v[j] * v[j]; }
    s = wave_sum64(s);
    float inv = 1.f / fmaxf(sqrtf(s), 1e-4f);
    int h = row / K_DIM, k = row % K_DIM;
    __hip_bfloat16* d1 = wb + (size_t)(k * H_DIM + h) * IN_DIM;
    __hip_bfloat16* d2 = wb2 + (size_t)h * NKH + k * IN_DIM;
    #pragma unroll
    for (int j = 0; j < 4; ++j) {
        __hip_bfloat16 t = __float2bfloat16(v[j] * inv);
        d1[lane + 64 * j] = t;
        d2[lane + 64 * j] = t;
    }
}

// ---- x row norms + bf16 copy; xninfo[2r]=norm, xninfo[2r+1]=1/max(norm,eps)
__global__ __launch_bounds__(256) void xnorm_kernel(const float* __restrict__ x,
        float* __restrict__ xninfo, __hip_bfloat16* __restrict__ xb) {
    int wv = threadIdx.x >> 6, lane = threadIdx.x & 63;
    int row = blockIdx.x * 4 + wv;                     // 0..16383
    const float* src = x + (size_t)row * IN_DIM;
    float v[4]; float s = 0.f;
    #pragma unroll
    for (int j = 0; j < 4; ++j) { v[j] = src[lane + 64 * j]; s += v[j] * v[j]; }
    s = wave_sum64(s);
    float nrm = sqrtf(s);
    if (lane == 0) { xninfo[2 * row] = nrm; xninfo[2 * row + 1] = 1.f / fmaxf(nrm, 1e-4f); }
    __hip_bfloat16* d = xb + (size_t)row * IN_DIM;
    #pragma unroll
    for (int j = 0; j < 4; ++j) d[lane + 64 * j] = __float2bfloat16(v[j]);
}

// ---- big GEMM via bf16 MFMA + kappa epilogue -> bmat bf16 [t][b][k][h] ----
__global__ __launch_bounds__(256) void gemm_b_mfma(const __hip_bfloat16* __restrict__ xb,
        const __hip_bfloat16* __restrict__ wb, const float* __restrict__ xninfo,
        __hip_bfloat16* __restrict__ bmat) {
    __shared__ __hip_bfloat16 As[4096];   // [128][32]
    __shared__ __hip_bfloat16 Bs[4096];
    int tid = threadIdx.x;
    int wid = tid >> 6, lane = tid & 63;
    int m0 = blockIdx.x * 128, n0 = blockIdx.y * 128;
    int wr = wid >> 1, wc = wid & 1;
    int srow = tid >> 2;
    int scol = (tid & 3) * 8;
    f32x4 acc[4][4] = {};

    for (int kb = 0; kb < IN_DIM; kb += 32) {
        #pragma unroll
        for (int half = 0; half < 2; ++half) {
            const __hip_bfloat16* ga = xb + (size_t)(m0 + half * 64 + srow) * IN_DIM + kb + scol;
            const __hip_bfloat16* gb = wb + (size_t)(n0 + half * 64 + srow) * IN_DIM + kb + scol;
            __builtin_amdgcn_global_load_lds((const GLOBAL_AS void*)ga,
                (LDS_AS void*)(As + half * 2048 + wid * 512), 16, 0, 0);
            __builtin_amdgcn_global_load_lds((const GLOBAL_AS void*)gb,
                (LDS_AS void*)(Bs + half * 2048 + wid * 512), 16, 0, 0);
        }
        __syncthreads();
        int seg = (lane >> 4) * 8;
        int rl = lane & 15;
        short8 a[4], b[4];
        #pragma unroll
        for (int m = 0; m < 4; ++m)
            a[m] = *(const short8*)(As + (wr * 64 + m * 16 + rl) * 32 + seg);
        #pragma unroll
        for (int n = 0; n < 4; ++n)
            b[n] = *(const short8*)(Bs + (wc * 64 + n * 16 + rl) * 32 + seg);
        #pragma unroll
        for (int m = 0; m < 4; ++m)
            #pragma unroll
            for (int n = 0; n < 4; ++n)
                acc[m][n] = __builtin_amdgcn_mfma_f32_16x16x32_bf16(a[m], b[n], acc[m][n], 0, 0, 0);
        __syncthreads();
    }

    int kk = blockIdx.y >> 1;
    int col_l = lane & 15;
    int rseg = (lane >> 4) * 4;
    #pragma unroll
    for (int m = 0; m < 4; ++m) {
        int rbase = m0 + wr * 64 + m * 16 + rseg;
        float4 q0 = *(const float4*)(xninfo + 2 * rbase);
        float4 q1 = *(const float4*)(xninfo + 2 * rbase + 4);
        float nrm[4] = { q0.x, q0.z, q1.x, q1.z };
        float inv[4] = { q0.y, q0.w, q1.y, q1.w };
        #pragma unroll
        for (int n = 0; n < 4; ++n) {
            int col = n0 + wc * 64 + n * 16 + col_l;
            int h = col & 255;
            #pragma unroll
            for (int j = 0; j < 4; ++j) {
                float bv = nrm[j] * __expf(0.4f * acc[m][n][j] * inv[j] - 0.4f);
                bmat[((size_t)(rbase + j) * K_DIM + kk) * H_DIM + h] = __float2bfloat16(bv);
            }
        }
    }
}

// ---- Gram via bf16 MFMA: M[h][g] = exp(0.4*dot(wb2[h],wb2[g]) - 4); rsum += row sums ----
__global__ __launch_bounds__(256) void gram_mfma(const __hip_bfloat16* __restrict__ wb2,
        float* __restrict__ Mm, float* __restrict__ rsum) {
    __shared__ __hip_bfloat16 As[4096];   // [128][32]
    __shared__ __hip_bfloat16 Bs[4096];
    int tid = threadIdx.x;
    int wid = tid >> 6, lane = tid & 63;
    int m0 = blockIdx.x * 128, n0 = blockIdx.y * 128;
    int wr = wid >> 1, wc = wid & 1;
    int srow = tid >> 2;
    int scol = (tid & 3) * 8;
    f32x4 acc[4][4] = {};

    for (int kb = 0; kb < NKH; kb += 32) {
        #pragma unroll
        for (int half = 0; half < 2; ++half) {
            const __hip_bfloat16* ga = wb2 + (size_t)(m0 + half * 64 + srow) * NKH + kb + scol;
            const __hip_bfloat16* gb = wb2 + (size_t)(n0 + half * 64 + srow) * NKH + kb + scol;
            __builtin_amdgcn_global_load_lds((const GLOBAL_AS void*)ga,
                (LDS_AS void*)(As + half * 2048 + wid * 512), 16, 0, 0);
            __builtin_amdgcn_global_load_lds((const GLOBAL_AS void*)gb,
                (LDS_AS void*)(Bs + half * 2048 + wid * 512), 16, 0, 0);
        }
        __syncthreads();
        int seg = (lane >> 4) * 8;
        int rl = lane & 15;
        short8 a[4], b[4];
        #pragma unroll
        for (int m = 0; m < 4; ++m)
            a[m] = *(const short8*)(As + (wr * 64 + m * 16 + rl) * 32 + seg);
        #pragma unroll
        for (int n = 0; n < 4; ++n)
            b[n] = *(const short8*)(Bs + (wc * 64 + n * 16 + rl) * 32 + seg);
        #pragma unroll
        for (int m = 0; m < 4; ++m)
            #pragma unroll
            for (int n = 0; n < 4; ++n)
                acc[m][n] = __builtin_amdgcn_mfma_f32_16x16x32_bf16(a[m], b[n], acc[m][n], 0, 0, 0);
        __syncthreads();
    }

    int col_l = lane & 15;
    int rseg = (lane >> 4) * 4;
    float rpart[4][4];
    #pragma unroll
    for (int m = 0; m < 4; ++m) {
        int rbase = m0 + wr * 64 + m * 16 + rseg;
        #pragma unroll
        for (int j = 0; j < 4; ++j) rpart[m][j] = 0.f;
        #pragma unroll
        for (int n = 0; n < 4; ++n) {
            int col = n0 + wc * 64 + n * 16 + col_l;
            #pragma unroll
            for (int j = 0; j < 4; ++j) {
                float e = __expf(0.4f * acc[m][n][j] - 4.0f);
                Mm[(size_t)(rbase + j) * H_DIM + col] = e;
                rpart[m][j] += e;
            }
        }
    }
    // reduce row partials across the 16 lanes sharing the same rows (col_l groups)
    #pragma unroll
    for (int off = 1; off < 16; off <<= 1)
        #pragma unroll
        for (int m = 0; m < 4; ++m)
            #pragma unroll
            for (int j = 0; j < 4; ++j)
                rpart[m][j] += __shfl_xor(rpart[m][j], off, 64);
    if (col_l == 0) {
        #pragma unroll
        for (int m = 0; m < 4; ++m) {
            int rbase = m0 + wr * 64 + m * 16 + rseg;
            #pragma unroll
            for (int j = 0; j < 4; ++j)
                atomicAdd(&rsum[rbase + j], rpart[m][j]);
        }
    }
}

// ---- recurrence with warm-up chunks ----
__global__ __launch_bounds__(256) void rec_kernel(const __hip_bfloat16* __restrict__ bmat,
        float* __restrict__ cs9, float* __restrict__ part, float* __restrict__ hxT) {
    int s = blockIdx.x >> 5;
    int b = blockIdx.x & 31;
    int h = threadIdx.x;
    int tout0 = s * 64;
    int t0 = (s == 0) ? 0 : tout0 - 64;
    int t1 = tout0 + 64;
    float c[10] = {};
    float s9 = 0.f;
    float bt[10];
    {
        const __hip_bfloat16* bp = bmat + ((size_t)(t0 * B_DIM + b) * K_DIM) * H_DIM + h;
        #pragma unroll
        for (int k = 0; k < 10; ++k) bt[k] = __bfloat162float(bp[k * H_DIM]);
    }
    for (int t = t0; t < t1; ++t) {
        int tn = (t + 1 < t1) ? t + 1 : t;
        float btn[10];
        const __hip_bfloat16* bq = bmat + ((size_t)(tn * B_DIM + b) * K_DIM) * H_DIM + h;
        #pragma unroll
        for (int k = 0; k < 10; ++k) btn[k] = __bfloat162float(bq[k * H_DIM]);
        #pragma unroll
        for (int j = 9; j >= 1; --j) c[j] = 0.5f * c[j] + c[j - 1] * bt[j];
        c[0] = 0.5f * c[0] + bt[0];
        if (t >= tout0) {
            cs9[(size_t)(t * B_DIM + b) * H_DIM + h] = c[9];
            s9 += c[9];
        }
        #pragma unroll
        for (int k = 0; k < 10; ++k) bt[k] = btn[k];
    }
    part[(size_t)(s * B_DIM + b) * H_DIM + h] = s9;
    if (s == 7) {
        float* hp = hxT + (size_t)(b * H_DIM + h) * K_DIM;
        #pragma unroll
        for (int k = 0; k < 10; ++k) hp[k] = c[k];
    }
}

__global__ __launch_bounds__(256) void recred_kernel(const float* __restrict__ part,
        float* __restrict__ mean9) {
    int i = blockIdx.x * 256 + threadIdx.x;            // 0..8191
    float s = 0.f;
    #pragma unroll
    for (int j = 0; j < 8; ++j) s += part[(size_t)j * 8192 + i];
    mean9[i] = s * (1.f / T_DIM);
}

// ---- cooperative lintrans: rowmax + init + 7 NS iterations + out0 projection ----
// 32x32 tile of C = A@B over K=256 (A,B 256x256 row-major), per block.
__device__ __forceinline__ void mm_tile32(const float* __restrict__ A, const float* __restrict__ B,
        float* __restrict__ C, int bi, int bj, int mode,
        float (*As)[260], float (*Bs)[32]) {
    int tid = threadIdx.x;
    int r0 = bi * 32, c0 = bj * 32;
    __syncthreads();   // previous use of LDS done
    #pragma unroll
    for (int i = 0; i < 8; ++i) {
        int f = tid + i * 256;
        int row = f >> 6, kc = (f & 63) << 2;
        float4 v = *(const float4*)(A + (size_t)(r0 + row) * 256 + kc);
        *(float4*)(&As[row][kc]) = v;
    }
    #pragma unroll
    for (int i = 0; i < 8; ++i) {
        int f = tid + i * 256;
        int k = f >> 3, cc = (f & 7) << 2;
        float4 v = *(const float4*)(B + (size_t)k * 256 + c0 + cc);
        *(float4*)(&Bs[k][cc]) = v;
    }
    __syncthreads();
    int c2 = (tid & 15) * 2, r2 = (tid >> 4) * 2;
    float acc00 = 0, acc01 = 0, acc10 = 0, acc11 = 0;
    for (int k = 0; k < 256; k += 4) {
        float4 a0 = *(const float4*)(&As[r2][k]);
        float4 a1 = *(const float4*)(&As[r2 + 1][k]);
        float2 b0 = *(const float2*)(&Bs[k + 0][c2]);
        float2 b1 = *(const float2*)(&Bs[k + 1][c2]);
        float2 b2 = *(const float2*)(&Bs[k + 2][c2]);
        float2 b3 = *(const float2*)(&Bs[k + 3][c2]);
        acc00 = fmaf(a0.x, b0.x, acc00); acc01 = fmaf(a0.x, b0.y, acc01);
        acc10 = fmaf(a1.x, b0.x, acc10); acc11 = fmaf(a1.x, b0.y, acc11);
        acc00 = fmaf(a0.y, b1.x, acc00); acc01 = fmaf(a0.y, b1.y, acc01);
        acc10 = fmaf(a1.y, b1.x, acc10); acc11 = fmaf(a1.y, b1.y, acc11);
        acc00 = fmaf(a0.z, b2.x, acc00); acc01 = fmaf(a0.z, b2.y, acc01);
        acc10 = fmaf(a1.z, b2.x, acc10); acc11 = fmaf(a1.z, b2.y, acc11);
        acc00 = fmaf(a0.w, b3.x, acc00); acc01 = fmaf(a0.w, b3.y, acc01);
        acc10 = fmaf(a1.w, b3.x, acc10); acc11 = fmaf(a1.w, b3.y, acc11);
    }
    int rr = r0 + r2, cc = c0 + c2;
    if (mode == 0) {   // W = 3I - acc
        C[(size_t)rr * 256 + cc]           = ((rr == cc)         ? 3.f : 0.f) - acc00;
        C[(size_t)rr * 256 + cc + 1]       = ((rr == cc + 1)     ? 3.f : 0.f) - acc01;
        C[(size_t)(rr + 1) * 256 + cc]     = ((rr + 1 == cc)     ? 3.f : 0.f) - acc10;
        C[(size_t)(rr + 1) * 256 + cc + 1] = ((rr + 1 == cc + 1) ? 3.f : 0.f) - acc11;
    } else {           // 0.5 * acc
        C[(size_t)rr * 256 + cc]           = 0.5f * acc00;
        C[(size_t)rr * 256 + cc + 1]       = 0.5f * acc01;
        C[(size_t)(rr + 1) * 256 + cc]     = 0.5f * acc10;
        C[(size_t)(rr + 1) * 256 + cc + 1] = 0.5f * acc11;
    }
}

__global__ __launch_bounds__(256) void coop_lintrans(
        const float* __restrict__ Mm, const float* __restrict__ rsum,
        float* __restrict__ Y0, float* __restrict__ Z0,
        float* __restrict__ Y1, float* __restrict__ Z1,
        float* __restrict__ Wb, const float* __restrict__ mean9,
        float* __restrict__ out0, float* __restrict__ cbuf) {
    __shared__ float As[32][260];
    __shared__ float Bs[256][32];
    __shared__ float red[256];
    cg::grid_group grid = cg::this_grid();
    int tid = threadIdx.x, blk = blockIdx.x;

    red[tid] = rsum[tid];
    __syncthreads();
    #pragma unroll
    for (int st = 128; st > 0; st >>= 1) {
        if (tid < st) red[tid] = fmaxf(red[tid], red[tid + st]);
        __syncthreads();
    }
    float c = red[0];
    float invc = 1.f / c, isq = rsqrtf(c);
    if (blk == 0 && tid == 0) { cbuf[0] = c; cbuf[1] = invc; cbuf[2] = isq; }

    int base = blk * 1024;
    #pragma unroll
    for (int i = 0; i < 4; ++i) {
        int idx = base + i * 256 + tid;
        Y0[idx] = Mm[idx] * invc;
        Z0[idx] = ((idx >> 8) == (idx & 255)) ? 1.f : 0.f;
    }
    grid.sync();

    float *Y = Y0, *Z = Z0, *Yn = Y1, *Zn = Z1;
    int bi = blk >> 3, bj = blk & 7;
    for (int it = 0; it < NS_ITERS; ++it) {
        mm_tile32(Z, Y, Wb, bi, bj, 0, As, Bs);      // W = 3I - Z@Y
        grid.sync();
        mm_tile32(Y, Wb, Yn, bi, bj, 1, As, Bs);     // Yn = 0.5*Y@W
        mm_tile32(Wb, Z, Zn, bi, bj, 1, As, Bs);     // Zn = 0.5*W@Z
        grid.sync();
        float* t = Y; Y = Yn; Yn = t;
        t = Z; Z = Zn; Zn = t;
    }
    // out0[b][g] = isq * sum_h mean9[b][h] * Z[h][g]
    int b = blk >> 1;
    int g = (blk & 1) * 128 + (tid & 127);
    int hh = tid >> 7;
    float acc = 0.f;
    const float* mrow = mean9 + b * 256;
    #pragma unroll 8
    for (int h = hh * 128; h < hh * 128 + 128; ++h)
        acc = fmaf(mrow[h], Z[(size_t)h * 256 + g], acc);
    __syncthreads();
    red[tid] = acc;
    __syncthreads();
    if (tid < 128) out0[b * 256 + (blk & 1) * 128 + tid] = (red[tid] + red[tid + 128]) * isq;
}

// ---- fp32 64x64 tile MM for out1 = cs9 @ lin * cbuf[2] ----
__device__ __forceinline__ void mm64_core(const float* __restrict__ A, const float* __restrict__ B,
        float As[16][64], float Bs[16][64], int m0, int n0, float acc[4][4]) {
    int tx = threadIdx.x & 15, ty = threadIdx.x >> 4;
    int lr = threadIdx.x >> 2, lc = (threadIdx.x & 3) * 4;
    int cb = threadIdx.x >> 6, jb = threadIdx.x & 63;
    for (int kb = 0; kb < 256; kb += 16) {
        float4 a4 = *(const float4*)(A + (size_t)(m0 + lr) * 256 + kb + lc);
        float b0 = B[(size_t)(kb + cb +  0) * 256 + n0 + jb];
        float b1 = B[(size_t)(kb + cb +  4) * 256 + n0 + jb];
        float b2 = B[(size_t)(kb + cb +  8) * 256 + n0 + jb];
        float b3 = B[(size_t)(kb + cb + 12) * 256 + n0 + jb];
        __syncthreads();
        As[lc+0][lr]=a4.x; As[lc+1][lr]=a4.y; As[lc+2][lr]=a4.z; As[lc+3][lr]=a4.w;
        Bs[cb][jb]=b0; Bs[cb+4][jb]=b1; Bs[cb+8][jb]=b2; Bs[cb+12][jb]=b3;
        __syncthreads();
        #pragma unroll
        for (int kc = 0; kc < 16; ++kc) {
            float a_[4], b_[4];
            #pragma unroll
            for (int i = 0; i < 4; ++i) a_[i] = As[kc][ty * 4 + i];
            #pragma unroll
            for (int j = 0; j < 4; ++j) b_[j] = Bs[kc][tx * 4 + j];
            #pragma unroll
            for (int i = 0; i < 4; ++i)
                #pragma unroll
                for (int j = 0; j < 4; ++j) acc[i][j] = fmaf(a_[i], b_[j], acc[i][j]);
        }
    }
}

__global__ __launch_bounds__(256) void mm_out1_kernel(const float* __restrict__ A,
        const float* __restrict__ B, float* __restrict__ C,
        const float* __restrict__ cbuf) {
    __shared__ float As[16][64], Bs[16][64];
    int m0 = blockIdx.x * 64, n0 = blockIdx.y * 64;
    float acc[4][4] = {};
    mm64_core(A, B, As, Bs, m0, n0, acc);
    int tx = threadIdx.x & 15, ty = threadIdx.x >> 4;
    float scale = cbuf[2];
    #pragma unroll
    for (int i = 0; i < 4; ++i) {
        float* crow = C + (size_t)(m0 + ty * 4 + i) * 256 + n0 + tx * 4;
        #pragma unroll
        for (int j = 0; j < 4; ++j) crow[j] = acc[i][j] * scale;
    }
}

extern "C" void kernel_launch(void* const* d_in, const int* in_sizes, int n_in,
                              void* d_out, int out_size, void* d_ws, size_t ws_size,
                              hipStream_t stream) {
    const float* x = (const float*)d_in[0];
    const float* w = (const float*)d_in[1];
    float* out0 = (float*)d_out;                       // B*H
    float* out1 = out0 + (size_t)B_DIM * H_DIM;        // T*B*H
    float* hxT  = out1 + (size_t)TB * H_DIM;           // B*H*K

    char* ws = (char*)d_ws;
    __hip_bfloat16* wb   = (__hip_bfloat16*)(ws + 0);         // 1,310,720
    __hip_bfloat16* wb2  = (__hip_bfloat16*)(ws + 1310720);   // 1,310,720
    float* xninfo        = (float*)(ws + 2621440);            //   131,072
    float* Mm            = (float*)(ws + 2752512);            //   262,144
    float* rsum          = (float*)(ws + 3014656);            //     1,024
    float* Y0            = (float*)(ws + 3015680);            //   262,144
    float* Z0            = (float*)(ws + 3277824);            //   262,144
    float* Y1            = (float*)(ws + 3539968);            //   262,144
    float* Z1            = (float*)(ws + 3802112);            //   262,144
    float* Wb            = (float*)(ws + 4064256);            //   262,144
    float* cbuf          = (float*)(ws + 4326400);            //     1,024
    float* mean9         = (float*)(ws + 4327424);            //    32,768
    float* part          = (float*)(ws + 4360192);            //   262,144
    float* cs9           = (float*)(ws + 4622336);            // 16,777,216
    __hip_bfloat16* xb   = (__hip_bfloat16*)cs9;              // aliases cs9 (dead before rec writes)
    __hip_bfloat16* bmat = (__hip_bfloat16*)(ws + 21399552);  // 83,886,080 -> total ~105 MB

    hipMemsetAsync(rsum, 0, H_DIM * sizeof(float), stream);
    wnorm_kernel<<<dim3(640), dim3(256), 0, stream>>>(w, wb, wb2);
    xnorm_kernel<<<dim3(4096), dim3(256), 0, stream>>>(x, xninfo, xb);
    gemm_b_mfma<<<dim3(128, 20), dim3(256), 0, stream>>>(xb, wb, xninfo, bmat);
    gram_mfma<<<dim3(2, 2), dim3(256), 0, stream>>>(wb2, Mm, rsum);
    rec_kernel<<<dim3(256), dim3(256), 0, stream>>>(bmat, cs9, part, hxT);
    recred_kernel<<<dim3(32), dim3(256), 0, stream>>>(part, mean9);

    void* args[] = { (void*)&Mm, (void*)&rsum, (void*)&Y0, (void*)&Z0, (void*)&Y1,
                     (void*)&Z1, (void*)&Wb, (void*)&mean9, (void*)&out0, (void*)&cbuf };
    hipLaunchCooperativeKernel((void*)coop_lintrans, dim3(64), dim3(256), args, 0, stream);

    // final Z after 7 iterations (odd count) lives in Z1
    mm_out1_kernel<<<dim3(256, 4), dim3(256), 0, stream>>>(cs9, Z1, out1, cbuf);
}

// Round 4
// 340.695 us; speedup vs baseline: 2.1834x; 1.3071x over previous
//
#include <hip/hip_runtime.h>
#include <hip/hip_bf16.h>
#include <hip/hip_cooperative_groups.h>

namespace cg = cooperative_groups;

// Problem dims
#define T_DIM 512
#define B_DIM 32
#define IN_DIM 256
#define H_DIM 256
#define K_DIM 10
#define TB 16384          // T*B
#define NKH 2560          // H*K
#define NPOW 6            // power-iteration updates

typedef __attribute__((ext_vector_type(8))) short short8;
typedef __attribute__((ext_vector_type(4))) float f32x4;

#define GLOBAL_AS __attribute__((address_space(1)))
#define LDS_AS __attribute__((address_space(3)))

__device__ __forceinline__ float wave_sum64(float v) {
    #pragma unroll
    for (int off = 32; off > 0; off >>= 1) v += __shfl_xor(v, off, 64);
    return v;
}

// ---- weight normalize: wb bf16 [(k*256+h)][256] (for gemm_b), wb2 bf16 [h][k*256+i] (for gram)
__global__ __launch_bounds__(256) void wnorm_kernel(const float* __restrict__ w,
        __hip_bfloat16* __restrict__ wb, __hip_bfloat16* __restrict__ wb2) {
    int wv = threadIdx.x >> 6, lane = threadIdx.x & 63;
    int row = blockIdx.x * 4 + wv;                     // 0..2559  (= h*10+k)
    const float* src = w + (size_t)row * IN_DIM;
    float v[4]; float s = 0.f;
    #pragma unroll
    for (int j = 0; j < 4; ++j) { v[j] = src[lane + 64 * j]; s += v[j] * v[j]; }
    s = wave_sum64(s);
    float inv = 1.f / fmaxf(sqrtf(s), 1e-4f);
    int h = row / K_DIM, k = row % K_DIM;
    __hip_bfloat16* d1 = wb + (size_t)(k * H_DIM + h) * IN_DIM;
    __hip_bfloat16* d2 = wb2 + (size_t)h * NKH + k * IN_DIM;
    #pragma unroll
    for (int j = 0; j < 4; ++j) {
        __hip_bfloat16 t = __float2bfloat16(v[j] * inv);
        d1[lane + 64 * j] = t;
        d2[lane + 64 * j] = t;
    }
}

// ---- x row norms + bf16 copy; xninfo[2r]=norm, xninfo[2r+1]=1/max(norm,eps)
__global__ __launch_bounds__(256) void xnorm_kernel(const float* __restrict__ x,
        float* __restrict__ xninfo, __hip_bfloat16* __restrict__ xb) {
    int wv = threadIdx.x >> 6, lane = threadIdx.x & 63;
    int row = blockIdx.x * 4 + wv;                     // 0..16383
    const float* src = x + (size_t)row * IN_DIM;
    float v[4]; float s = 0.f;
    #pragma unroll
    for (int j = 0; j < 4; ++j) { v[j] = src[lane + 64 * j]; s += v[j] * v[j]; }
    s = wave_sum64(s);
    float nrm = sqrtf(s);
    if (lane == 0) { xninfo[2 * row] = nrm; xninfo[2 * row + 1] = 1.f / fmaxf(nrm, 1e-4f); }
    __hip_bfloat16* d = xb + (size_t)row * IN_DIM;
    #pragma unroll
    for (int j = 0; j < 4; ++j) d[lane + 64 * j] = __float2bfloat16(v[j]);
}

// ---- big GEMM via bf16 MFMA + kappa epilogue -> bmat bf16 [t][b][k][h] ----
__global__ __launch_bounds__(256) void gemm_b_mfma(const __hip_bfloat16* __restrict__ xb,
        const __hip_bfloat16* __restrict__ wb, const float* __restrict__ xninfo,
        __hip_bfloat16* __restrict__ bmat) {
    __shared__ __hip_bfloat16 As[4096];   // [128][32]
    __shared__ __hip_bfloat16 Bs[4096];
    int tid = threadIdx.x;
    int wid = tid >> 6, lane = tid & 63;
    int m0 = blockIdx.x * 128, n0 = blockIdx.y * 128;
    int wr = wid >> 1, wc = wid & 1;
    int srow = tid >> 2;
    int scol = (tid & 3) * 8;
    f32x4 acc[4][4] = {};

    for (int kb = 0; kb < IN_DIM; kb += 32) {
        #pragma unroll
        for (int half = 0; half < 2; ++half) {
            const __hip_bfloat16* ga = xb + (size_t)(m0 + half * 64 + srow) * IN_DIM + kb + scol;
            const __hip_bfloat16* gb = wb + (size_t)(n0 + half * 64 + srow) * IN_DIM + kb + scol;
            __builtin_amdgcn_global_load_lds((const GLOBAL_AS void*)ga,
                (LDS_AS void*)(As + half * 2048 + wid * 512), 16, 0, 0);
            __builtin_amdgcn_global_load_lds((const GLOBAL_AS void*)gb,
                (LDS_AS void*)(Bs + half * 2048 + wid * 512), 16, 0, 0);
        }
        __syncthreads();
        int seg = (lane >> 4) * 8;
        int rl = lane & 15;
        short8 a[4], b[4];
        #pragma unroll
        for (int m = 0; m < 4; ++m)
            a[m] = *(const short8*)(As + (wr * 64 + m * 16 + rl) * 32 + seg);
        #pragma unroll
        for (int n = 0; n < 4; ++n)
            b[n] = *(const short8*)(Bs + (wc * 64 + n * 16 + rl) * 32 + seg);
        #pragma unroll
        for (int m = 0; m < 4; ++m)
            #pragma unroll
            for (int n = 0; n < 4; ++n)
                acc[m][n] = __builtin_amdgcn_mfma_f32_16x16x32_bf16(a[m], b[n], acc[m][n], 0, 0, 0);
        __syncthreads();
    }

    int kk = blockIdx.y >> 1;
    int col_l = lane & 15;
    int rseg = (lane >> 4) * 4;
    #pragma unroll
    for (int m = 0; m < 4; ++m) {
        int rbase = m0 + wr * 64 + m * 16 + rseg;
        float4 q0 = *(const float4*)(xninfo + 2 * rbase);
        float4 q1 = *(const float4*)(xninfo + 2 * rbase + 4);
        float nrm[4] = { q0.x, q0.z, q1.x, q1.z };
        float inv[4] = { q0.y, q0.w, q1.y, q1.w };
        #pragma unroll
        for (int n = 0; n < 4; ++n) {
            int col = n0 + wc * 64 + n * 16 + col_l;
            int h = col & 255;
            #pragma unroll
            for (int j = 0; j < 4; ++j) {
                float bv = nrm[j] * __expf(0.4f * acc[m][n][j] * inv[j] - 0.4f);
                bmat[((size_t)(rbase + j) * K_DIM + kk) * H_DIM + h] = __float2bfloat16(bv);
            }
        }
    }
}

// ---- Gram via bf16 MFMA: M[h][g] = exp(0.4*dot(wb2[h],wb2[g]) - 4); rsum += row sums ----
__global__ __launch_bounds__(256) void gram_mfma(const __hip_bfloat16* __restrict__ wb2,
        float* __restrict__ Mm, float* __restrict__ rsum) {
    __shared__ __hip_bfloat16 As[4096];   // [128][32]
    __shared__ __hip_bfloat16 Bs[4096];
    int tid = threadIdx.x;
    int wid = tid >> 6, lane = tid & 63;
    int m0 = blockIdx.x * 128, n0 = blockIdx.y * 128;
    int wr = wid >> 1, wc = wid & 1;
    int srow = tid >> 2;
    int scol = (tid & 3) * 8;
    f32x4 acc[4][4] = {};

    for (int kb = 0; kb < NKH; kb += 32) {
        #pragma unroll
        for (int half = 0; half < 2; ++half) {
            const __hip_bfloat16* ga = wb2 + (size_t)(m0 + half * 64 + srow) * NKH + kb + scol;
            const __hip_bfloat16* gb = wb2 + (size_t)(n0 + half * 64 + srow) * NKH + kb + scol;
            __builtin_amdgcn_global_load_lds((const GLOBAL_AS void*)ga,
                (LDS_AS void*)(As + half * 2048 + wid * 512), 16, 0, 0);
            __builtin_amdgcn_global_load_lds((const GLOBAL_AS void*)gb,
                (LDS_AS void*)(Bs + half * 2048 + wid * 512), 16, 0, 0);
        }
        __syncthreads();
        int seg = (lane >> 4) * 8;
        int rl = lane & 15;
        short8 a[4], b[4];
        #pragma unroll
        for (int m = 0; m < 4; ++m)
            a[m] = *(const short8*)(As + (wr * 64 + m * 16 + rl) * 32 + seg);
        #pragma unroll
        for (int n = 0; n < 4; ++n)
            b[n] = *(const short8*)(Bs + (wc * 64 + n * 16 + rl) * 32 + seg);
        #pragma unroll
        for (int m = 0; m < 4; ++m)
            #pragma unroll
            for (int n = 0; n < 4; ++n)
                acc[m][n] = __builtin_amdgcn_mfma_f32_16x16x32_bf16(a[m], b[n], acc[m][n], 0, 0, 0);
        __syncthreads();
    }

    int col_l = lane & 15;
    int rseg = (lane >> 4) * 4;
    float rpart[4][4];
    #pragma unroll
    for (int m = 0; m < 4; ++m) {
        int rbase = m0 + wr * 64 + m * 16 + rseg;
        #pragma unroll
        for (int j = 0; j < 4; ++j) rpart[m][j] = 0.f;
        #pragma unroll
        for (int n = 0; n < 4; ++n) {
            int col = n0 + wc * 64 + n * 16 + col_l;
            #pragma unroll
            for (int j = 0; j < 4; ++j) {
                float e = __expf(0.4f * acc[m][n][j] - 4.0f);
                Mm[(size_t)(rbase + j) * H_DIM + col] = e;
                rpart[m][j] += e;
            }
        }
    }
    #pragma unroll
    for (int off = 1; off < 16; off <<= 1)
        #pragma unroll
        for (int m = 0; m < 4; ++m)
            #pragma unroll
            for (int j = 0; j < 4; ++j)
                rpart[m][j] += __shfl_xor(rpart[m][j], off, 64);
    if (col_l == 0) {
        #pragma unroll
        for (int m = 0; m < 4; ++m) {
            int rbase = m0 + wr * 64 + m * 16 + rseg;
            #pragma unroll
            for (int j = 0; j < 4; ++j)
                atomicAdd(&rsum[rbase + j], rpart[m][j]);
        }
    }
}

// ---- recurrence with warm-up chunks (warm-up 32: 0.5^32 ~ 2e-10 init error) ----
__global__ __launch_bounds__(256) void rec_kernel(const __hip_bfloat16* __restrict__ bmat,
        __hip_bfloat16* __restrict__ cs9b, float* __restrict__ part, float* __restrict__ hxT) {
    int s = blockIdx.x >> 5;
    int b = blockIdx.x & 31;
    int h = threadIdx.x;
    int tout0 = s * 64;
    int t0 = (s == 0) ? 0 : tout0 - 32;
    int t1 = tout0 + 64;
    float c[10] = {};
    float s9 = 0.f;
    float bt[10];
    {
        const __hip_bfloat16* bp = bmat + ((size_t)(t0 * B_DIM + b) * K_DIM) * H_DIM + h;
        #pragma unroll
        for (int k = 0; k < 10; ++k) bt[k] = __bfloat162float(bp[k * H_DIM]);
    }
    for (int t = t0; t < t1; ++t) {
        int tn = (t + 1 < t1) ? t + 1 : t;
        float btn[10];
        const __hip_bfloat16* bq = bmat + ((size_t)(tn * B_DIM + b) * K_DIM) * H_DIM + h;
        #pragma unroll
        for (int k = 0; k < 10; ++k) btn[k] = __bfloat162float(bq[k * H_DIM]);
        #pragma unroll
        for (int j = 9; j >= 1; --j) c[j] = 0.5f * c[j] + c[j - 1] * bt[j];
        c[0] = 0.5f * c[0] + bt[0];
        if (t >= tout0) {
            cs9b[(size_t)(t * B_DIM + b) * H_DIM + h] = __float2bfloat16(c[9]);
            s9 += c[9];
        }
        #pragma unroll
        for (int k = 0; k < 10; ++k) bt[k] = btn[k];
    }
    part[(size_t)(s * B_DIM + b) * H_DIM + h] = s9;
    if (s == 7) {
        float* hp = hxT + (size_t)(b * H_DIM + h) * K_DIM;
        #pragma unroll
        for (int k = 0; k < 10; ++k) hp[k] = c[k];
    }
}

__global__ __launch_bounds__(256) void recred_kernel(const float* __restrict__ part,
        float* __restrict__ mean9) {
    int i = blockIdx.x * 256 + threadIdx.x;            // 0..8191
    float s = 0.f;
    #pragma unroll
    for (int j = 0; j < 8; ++j) s += part[(size_t)j * 8192 + i];
    mean9[i] = s * (1.f / T_DIM);
}

// ---- 16x16 fp32 MM tile over K=256; one output per thread ----
__device__ __forceinline__ float mm16(const float* __restrict__ A, const float* __restrict__ B,
        int r0, int c0, float (*As)[260], float (*BsT)[260]) {
    int tid = threadIdx.x;
    __syncthreads();
    #pragma unroll
    for (int i = 0; i < 4; ++i) {
        int fi = tid + i * 256;
        int row = fi >> 6, k4 = (fi & 63) << 2;
        float4 v = *(const float4*)(A + (size_t)(r0 + row) * 256 + k4);
        *(float4*)(&As[row][k4]) = v;
    }
    #pragma unroll
    for (int i = 0; i < 4; ++i) {
        int fi = tid + i * 256;
        int k = fi >> 2, c4 = (fi & 3) << 2;
        float4 v = *(const float4*)(B + (size_t)k * 256 + c0 + c4);
        BsT[c4 + 0][k] = v.x; BsT[c4 + 1][k] = v.y;
        BsT[c4 + 2][k] = v.z; BsT[c4 + 3][k] = v.w;
    }
    __syncthreads();
    int r = tid >> 4, c = tid & 15;
    float a0 = 0, a1 = 0, a2 = 0, a3 = 0;
    #pragma unroll 8
    for (int k = 0; k < 256; k += 4) {
        float4 av = *(const float4*)(&As[r][k]);
        float4 bv = *(const float4*)(&BsT[c][k]);
        a0 = fmaf(av.x, bv.x, a0);
        a1 = fmaf(av.y, bv.y, a1);
        a2 = fmaf(av.z, bv.z, a2);
        a3 = fmaf(av.w, bv.w, a3);
    }
    return (a0 + a1) + (a2 + a3);
}

// ---- cooperative lintrans: power iteration + deflation + degree-4 Taylor ----
// lin = (I+E)^{-1/2} + (l1^{-1/2}-1) v v^T,  E = M - I - (l1-1) v v^T
// (I+E)^{-1/2} ~= [I - E/2 + 3/8 E2] + E2 @ [-5/16 E + 35/128 E2]
__global__ __launch_bounds__(256) void coop_lintrans(
        const float* __restrict__ Mm, const float* __restrict__ rsum,
        float* __restrict__ E, float* __restrict__ E2, float* __restrict__ F,
        float* __restrict__ lin, __hip_bfloat16* __restrict__ linb,
        float* __restrict__ vbuf, float* __restrict__ cbuf,
        const float* __restrict__ mean9, float* __restrict__ out0) {
    __shared__ float As[16][260];
    __shared__ float BsT[16][260];
    __shared__ float sred[256];
    cg::grid_group grid = cg::this_grid();
    int tid = threadIdx.x, blk = blockIdx.x;

    // ---- phase 1: power iteration (block 0 only) ----
    if (blk == 0) {
        float* v = &As[0][0];
        v[tid] = rsum[tid];          // rsum = M @ ones : already one power step
        __syncthreads();
        float lam = 1.f;
        for (int it = 0; it <= NPOW; ++it) {
            float acc = 0.f;
            const float* row = Mm + (size_t)tid * 256;
            #pragma unroll 8
            for (int g = 0; g < 256; ++g) acc = fmaf(row[g], v[g], acc);
            if (it < NPOW) {
                sred[tid] = acc * acc;
                __syncthreads();
                #pragma unroll
                for (int st = 128; st > 0; st >>= 1) {
                    if (tid < st) sred[tid] += sred[tid + st];
                    __syncthreads();
                }
                float inv = rsqrtf(sred[0]);
                __syncthreads();
                v[tid] = acc * inv;
                __syncthreads();
            } else {
                sred[tid] = acc * v[tid];     // ||v||=1 -> Rayleigh quotient
                __syncthreads();
                #pragma unroll
                for (int st = 128; st > 0; st >>= 1) {
                    if (tid < st) sred[tid] += sred[tid + st];
                    __syncthreads();
                }
                lam = sred[0];
            }
        }
        vbuf[tid] = v[tid];
        if (tid == 0) {
            cbuf[0] = lam;
            cbuf[1] = lam - 1.f;
            cbuf[2] = rsqrtf(lam) - 1.f;
        }
    }
    grid.sync();

    // ---- phase 2: E = M - I - (l1-1) v v^T  (block = row) ----
    {
        float lamm1 = cbuf[1];
        float e = Mm[(size_t)blk * 256 + tid] - ((blk == tid) ? 1.f : 0.f)
                - lamm1 * vbuf[blk] * vbuf[tid];
        E[(size_t)blk * 256 + tid] = e;
    }
    grid.sync();

    // ---- phase 3: E2 = E@E ; F = -5/16 E + 35/128 E2 ----
    int r0 = (blk >> 4) * 16, c0 = (blk & 15) * 16;
    int r = r0 + (tid >> 4), c = c0 + (tid & 15);
    size_t idx = (size_t)r * 256 + c;
    {
        float e2 = mm16(E, E, r0, c0, As, BsT);
        E2[idx] = e2;
        F[idx] = -0.3125f * E[idx] + 0.2734375f * e2;
    }
    grid.sync();

    // ---- phase 4: G = E2@F ; lin = I - E/2 + 3/8 E2 + G + lfac v v^T ----
    {
        float g = mm16(E2, F, r0, c0, As, BsT);
        float lv = ((r == c) ? 1.f : 0.f) - 0.5f * E[idx] + 0.375f * E2[idx] + g
                 + cbuf[2] * vbuf[r] * vbuf[c];
        lin[idx] = lv;
        linb[idx] = __float2bfloat16(lv);
    }
    grid.sync();

    // ---- phase 5: out0[b][g] = sum_h mean9[b][h] * lin[h][g] ----
    {
        int b = blk >> 3;
        int gc = (blk & 7) * 32 + (tid & 31);
        int h0 = (tid >> 5) * 32;
        const float* mrow = mean9 + b * 256;
        float acc = 0.f;
        #pragma unroll 8
        for (int h = h0; h < h0 + 32; ++h)
            acc = fmaf(mrow[h], lin[(size_t)h * 256 + gc], acc);
        __syncthreads();
        sred[tid] = acc;
        __syncthreads();
        if (tid < 32) {
            float s = 0.f;
            #pragma unroll
            for (int j = 0; j < 8; ++j) s += sred[tid + j * 32];
            out0[b * 256 + (blk & 7) * 32 + tid] = s;
        }
    }
}

// ---- out1 = cs9b @ linb via bf16 MFMA (lin symmetric -> row-major linb is B^T form) ----
__global__ __launch_bounds__(256) void mm_out1_mfma(const __hip_bfloat16* __restrict__ A,
        const __hip_bfloat16* __restrict__ Bt, float* __restrict__ C) {
    __shared__ __hip_bfloat16 As[4096];   // [128][32]
    __shared__ __hip_bfloat16 Bs[4096];
    int tid = threadIdx.x;
    int wid = tid >> 6, lane = tid & 63;
    int m0 = blockIdx.x * 128, n0 = blockIdx.y * 128;
    int wr = wid >> 1, wc = wid & 1;
    int srow = tid >> 2;
    int scol = (tid & 3) * 8;
    f32x4 acc[4][4] = {};

    for (int kb = 0; kb < 256; kb += 32) {
        #pragma unroll
        for (int half = 0; half < 2; ++half) {
            const __hip_bfloat16* ga = A + (size_t)(m0 + half * 64 + srow) * 256 + kb + scol;
            const __hip_bfloat16* gb = Bt + (size_t)(n0 + half * 64 + srow) * 256 + kb + scol;
            __builtin_amdgcn_global_load_lds((const GLOBAL_AS void*)ga,
                (LDS_AS void*)(As + half * 2048 + wid * 512), 16, 0, 0);
            __builtin_amdgcn_global_load_lds((const GLOBAL_AS void*)gb,
                (LDS_AS void*)(Bs + half * 2048 + wid * 512), 16, 0, 0);
        }
        __syncthreads();
        int seg = (lane >> 4) * 8;
        int rl = lane & 15;
        short8 a[4], b[4];
        #pragma unroll
        for (int m = 0; m < 4; ++m)
            a[m] = *(const short8*)(As + (wr * 64 + m * 16 + rl) * 32 + seg);
        #pragma unroll
        for (int n = 0; n < 4; ++n)
            b[n] = *(const short8*)(Bs + (wc * 64 + n * 16 + rl) * 32 + seg);
        #pragma unroll
        for (int m = 0; m < 4; ++m)
            #pragma unroll
            for (int n = 0; n < 4; ++n)
                acc[m][n] = __builtin_amdgcn_mfma_f32_16x16x32_bf16(a[m], b[n], acc[m][n], 0, 0, 0);
        __syncthreads();
    }

    int col_l = lane & 15;
    int rseg = (lane >> 4) * 4;
    #pragma unroll
    for (int m = 0; m < 4; ++m) {
        int rbase = m0 + wr * 64 + m * 16 + rseg;
        #pragma unroll
        for (int n = 0; n < 4; ++n) {
            int col = n0 + wc * 64 + n * 16 + col_l;
            #pragma unroll
            for (int j = 0; j < 4; ++j)
                C[(size_t)(rbase + j) * 256 + col] = acc[m][n][j];
        }
    }
}

extern "C" void kernel_launch(void* const* d_in, const int* in_sizes, int n_in,
                              void* d_out, int out_size, void* d_ws, size_t ws_size,
                              hipStream_t stream) {
    const float* x = (const float*)d_in[0];
    const float* w = (const float*)d_in[1];
    float* out0 = (float*)d_out;                       // B*H
    float* out1 = out0 + (size_t)B_DIM * H_DIM;        // T*B*H
    float* hxT  = out1 + (size_t)TB * H_DIM;           // B*H*K

    char* ws = (char*)d_ws;
    __hip_bfloat16* wb   = (__hip_bfloat16*)(ws + 0);          // 1,310,720
    __hip_bfloat16* wb2  = (__hip_bfloat16*)(ws + 1310720);    // 1,310,720
    float* xninfo        = (float*)(ws + 2621440);             //   131,072
    float* Mm            = (float*)(ws + 2752512);             //   262,144
    float* rsum          = (float*)(ws + 3014656);             //     1,024
    float* E             = (float*)(ws + 3015680);             //   262,144
    float* E2            = (float*)(ws + 3277824);             //   262,144
    float* F             = (float*)(ws + 3539968);             //   262,144
    float* lin           = (float*)(ws + 3802112);             //   262,144
    __hip_bfloat16* linb = (__hip_bfloat16*)(ws + 4064256);    //   131,072
    float* vbuf          = (float*)(ws + 4195328);             //     1,024
    float* cbuf          = (float*)(ws + 4196352);             //     1,024
    float* mean9         = (float*)(ws + 4197376);             //    32,768
    float* part          = (float*)(ws + 4230144);             //   262,144
    __hip_bfloat16* cs9b = (__hip_bfloat16*)(ws + 4492288);    // 8,388,608
    __hip_bfloat16* xb   = (__hip_bfloat16*)(ws + 12880896);   // 8,388,608
    __hip_bfloat16* bmat = (__hip_bfloat16*)(ws + 21269504);   // 83,886,080 -> ~100.3 MB

    hipMemsetAsync(rsum, 0, H_DIM * sizeof(float), stream);
    wnorm_kernel<<<dim3(640), dim3(256), 0, stream>>>(w, wb, wb2);
    xnorm_kernel<<<dim3(4096), dim3(256), 0, stream>>>(x, xninfo, xb);
    gemm_b_mfma<<<dim3(128, 20), dim3(256), 0, stream>>>(xb, wb, xninfo, bmat);
    gram_mfma<<<dim3(2, 2), dim3(256), 0, stream>>>(wb2, Mm, rsum);
    rec_kernel<<<dim3(256), dim3(256), 0, stream>>>(bmat, cs9b, part, hxT);
    recred_kernel<<<dim3(32), dim3(256), 0, stream>>>(part, mean9);

    void* args[] = { (void*)&Mm, (void*)&rsum, (void*)&E, (void*)&E2, (void*)&F,
                     (void*)&lin, (void*)&linb, (void*)&vbuf, (void*)&cbuf,
                     (void*)&mean9, (void*)&out0 };
    hipLaunchCooperativeKernel((void*)coop_lintrans, dim3(256), dim3(256), args, 0, stream);

    mm_out1_mfma<<<dim3(128, 2), dim3(256), 0, stream>>>(cs9b, linb, out1);
}

// Round 5
// 239.175 us; speedup vs baseline: 3.1102x; 1.4245x over previous
//
#include <hip/hip_runtime.h>
#include <hip/hip_bf16.h>

// Problem dims
#define T_DIM 512
#define B_DIM 32
#define IN_DIM 256
#define H_DIM 256
#define K_DIM 10
#define TB 16384          // T*B
#define NKH 2560          // H*K
#define NPOW 3            // normalized power updates (v0 = rsum = M@1 is already 1 step)

typedef __attribute__((ext_vector_type(8))) short short8;
typedef __attribute__((ext_vector_type(4))) float f32x4;

#define GLOBAL_AS __attribute__((address_space(1)))
#define LDS_AS __attribute__((address_space(3)))

__device__ __forceinline__ float wave_sum64(float v) {
    #pragma unroll
    for (int off = 32; off > 0; off >>= 1) v += __shfl_xor(v, off, 64);
    return v;
}

// ---- weight normalize: wb bf16 [(k*256+h)][256] (for gemm_b), wb2 bf16 [h][k*256+i] (for gram)
__global__ __launch_bounds__(256) void wnorm_kernel(const float* __restrict__ w,
        __hip_bfloat16* __restrict__ wb, __hip_bfloat16* __restrict__ wb2) {
    int wv = threadIdx.x >> 6, lane = threadIdx.x & 63;
    int row = blockIdx.x * 4 + wv;                     // 0..2559  (= h*10+k)
    const float* src = w + (size_t)row * IN_DIM;
    float v[4]; float s = 0.f;
    #pragma unroll
    for (int j = 0; j < 4; ++j) { v[j] = src[lane + 64 * j]; s += v[j] * v[j]; }
    s = wave_sum64(s);
    float inv = 1.f / fmaxf(sqrtf(s), 1e-4f);
    int h = row / K_DIM, k = row % K_DIM;
    __hip_bfloat16* d1 = wb + (size_t)(k * H_DIM + h) * IN_DIM;
    __hip_bfloat16* d2 = wb2 + (size_t)h * NKH + k * IN_DIM;
    #pragma unroll
    for (int j = 0; j < 4; ++j) {
        __hip_bfloat16 t = __float2bfloat16(v[j] * inv);
        d1[lane + 64 * j] = t;
        d2[lane + 64 * j] = t;
    }
}

// ---- x row norms + bf16 copy; xninfo[2r]=norm, xninfo[2r+1]=1/max(norm,eps)
__global__ __launch_bounds__(256) void xnorm_kernel(const float* __restrict__ x,
        float* __restrict__ xninfo, __hip_bfloat16* __restrict__ xb) {
    int wv = threadIdx.x >> 6, lane = threadIdx.x & 63;
    int row = blockIdx.x * 4 + wv;                     // 0..16383
    const float* src = x + (size_t)row * IN_DIM;
    float v[4]; float s = 0.f;
    #pragma unroll
    for (int j = 0; j < 4; ++j) { v[j] = src[lane + 64 * j]; s += v[j] * v[j]; }
    s = wave_sum64(s);
    float nrm = sqrtf(s);
    if (lane == 0) { xninfo[2 * row] = nrm; xninfo[2 * row + 1] = 1.f / fmaxf(nrm, 1e-4f); }
    __hip_bfloat16* d = xb + (size_t)row * IN_DIM;
    #pragma unroll
    for (int j = 0; j < 4; ++j) d[lane + 64 * j] = __float2bfloat16(v[j]);
}

// ---- big GEMM via bf16 MFMA + kappa epilogue -> bmat bf16 [t][b][k][h] ----
__global__ __launch_bounds__(256) void gemm_b_mfma(const __hip_bfloat16* __restrict__ xb,
        const __hip_bfloat16* __restrict__ wb, const float* __restrict__ xninfo,
        __hip_bfloat16* __restrict__ bmat) {
    __shared__ __hip_bfloat16 As[4096];   // [128][32]
    __shared__ __hip_bfloat16 Bs[4096];
    int tid = threadIdx.x;
    int wid = tid >> 6, lane = tid & 63;
    int m0 = blockIdx.x * 128, n0 = blockIdx.y * 128;
    int wr = wid >> 1, wc = wid & 1;
    int srow = tid >> 2;
    int scol = (tid & 3) * 8;
    f32x4 acc[4][4] = {};

    for (int kb = 0; kb < IN_DIM; kb += 32) {
        #pragma unroll
        for (int half = 0; half < 2; ++half) {
            const __hip_bfloat16* ga = xb + (size_t)(m0 + half * 64 + srow) * IN_DIM + kb + scol;
            const __hip_bfloat16* gb = wb + (size_t)(n0 + half * 64 + srow) * IN_DIM + kb + scol;
            __builtin_amdgcn_global_load_lds((const GLOBAL_AS void*)ga,
                (LDS_AS void*)(As + half * 2048 + wid * 512), 16, 0, 0);
            __builtin_amdgcn_global_load_lds((const GLOBAL_AS void*)gb,
                (LDS_AS void*)(Bs + half * 2048 + wid * 512), 16, 0, 0);
        }
        __syncthreads();
        int seg = (lane >> 4) * 8;
        int rl = lane & 15;
        short8 a[4], b[4];
        #pragma unroll
        for (int m = 0; m < 4; ++m)
            a[m] = *(const short8*)(As + (wr * 64 + m * 16 + rl) * 32 + seg);
        #pragma unroll
        for (int n = 0; n < 4; ++n)
            b[n] = *(const short8*)(Bs + (wc * 64 + n * 16 + rl) * 32 + seg);
        #pragma unroll
        for (int m = 0; m < 4; ++m)
            #pragma unroll
            for (int n = 0; n < 4; ++n)
                acc[m][n] = __builtin_amdgcn_mfma_f32_16x16x32_bf16(a[m], b[n], acc[m][n], 0, 0, 0);
        __syncthreads();
    }

    int kk = blockIdx.y >> 1;
    int col_l = lane & 15;
    int rseg = (lane >> 4) * 4;
    #pragma unroll
    for (int m = 0; m < 4; ++m) {
        int rbase = m0 + wr * 64 + m * 16 + rseg;
        float4 q0 = *(const float4*)(xninfo + 2 * rbase);
        float4 q1 = *(const float4*)(xninfo + 2 * rbase + 4);
        float nrm[4] = { q0.x, q0.z, q1.x, q1.z };
        float inv[4] = { q0.y, q0.w, q1.y, q1.w };
        #pragma unroll
        for (int n = 0; n < 4; ++n) {
            int col = n0 + wc * 64 + n * 16 + col_l;
            int h = col & 255;
            #pragma unroll
            for (int j = 0; j < 4; ++j) {
                float bv = nrm[j] * __expf(0.4f * acc[m][n][j] * inv[j] - 0.4f);
                bmat[((size_t)(rbase + j) * K_DIM + kk) * H_DIM + h] = __float2bfloat16(bv);
            }
        }
    }
}

// ---- Gram via bf16 MFMA: M[h][g] = exp(0.4*dot(wb2[h],wb2[g]) - 4); rsum += row sums ----
__global__ __launch_bounds__(256) void gram_mfma(const __hip_bfloat16* __restrict__ wb2,
        float* __restrict__ Mm, float* __restrict__ rsum) {
    __shared__ __hip_bfloat16 As[4096];   // [128][32]
    __shared__ __hip_bfloat16 Bs[4096];
    int tid = threadIdx.x;
    int wid = tid >> 6, lane = tid & 63;
    int m0 = blockIdx.x * 128, n0 = blockIdx.y * 128;
    int wr = wid >> 1, wc = wid & 1;
    int srow = tid >> 2;
    int scol = (tid & 3) * 8;
    f32x4 acc[4][4] = {};

    for (int kb = 0; kb < NKH; kb += 32) {
        #pragma unroll
        for (int half = 0; half < 2; ++half) {
            const __hip_bfloat16* ga = wb2 + (size_t)(m0 + half * 64 + srow) * NKH + kb + scol;
            const __hip_bfloat16* gb = wb2 + (size_t)(n0 + half * 64 + srow) * NKH + kb + scol;
            __builtin_amdgcn_global_load_lds((const GLOBAL_AS void*)ga,
                (LDS_AS void*)(As + half * 2048 + wid * 512), 16, 0, 0);
            __builtin_amdgcn_global_load_lds((const GLOBAL_AS void*)gb,
                (LDS_AS void*)(Bs + half * 2048 + wid * 512), 16, 0, 0);
        }
        __syncthreads();
        int seg = (lane >> 4) * 8;
        int rl = lane & 15;
        short8 a[4], b[4];
        #pragma unroll
        for (int m = 0; m < 4; ++m)
            a[m] = *(const short8*)(As + (wr * 64 + m * 16 + rl) * 32 + seg);
        #pragma unroll
        for (int n = 0; n < 4; ++n)
            b[n] = *(const short8*)(Bs + (wc * 64 + n * 16 + rl) * 32 + seg);
        #pragma unroll
        for (int m = 0; m < 4; ++m)
            #pragma unroll
            for (int n = 0; n < 4; ++n)
                acc[m][n] = __builtin_amdgcn_mfma_f32_16x16x32_bf16(a[m], b[n], acc[m][n], 0, 0, 0);
        __syncthreads();
    }

    int col_l = lane & 15;
    int rseg = (lane >> 4) * 4;
    float rpart[4][4];
    #pragma unroll
    for (int m = 0; m < 4; ++m) {
        int rbase = m0 + wr * 64 + m * 16 + rseg;
        #pragma unroll
        for (int j = 0; j < 4; ++j) rpart[m][j] = 0.f;
        #pragma unroll
        for (int n = 0; n < 4; ++n) {
            int col = n0 + wc * 64 + n * 16 + col_l;
            #pragma unroll
            for (int j = 0; j < 4; ++j) {
                float e = __expf(0.4f * acc[m][n][j] - 4.0f);
                Mm[(size_t)(rbase + j) * H_DIM + col] = e;
                rpart[m][j] += e;
            }
        }
    }
    #pragma unroll
    for (int off = 1; off < 16; off <<= 1)
        #pragma unroll
        for (int m = 0; m < 4; ++m)
            #pragma unroll
            for (int j = 0; j < 4; ++j)
                rpart[m][j] += __shfl_xor(rpart[m][j], off, 64);
    if (col_l == 0) {
        #pragma unroll
        for (int m = 0; m < 4; ++m) {
            int rbase = m0 + wr * 64 + m * 16 + rseg;
            #pragma unroll
            for (int j = 0; j < 4; ++j)
                atomicAdd(&rsum[rbase + j], rpart[m][j]);
        }
    }
}

// ---- recurrence with warm-up chunks (warm-up 32: 0.5^32 ~ 2e-10 init error) ----
__global__ __launch_bounds__(256) void rec_kernel(const __hip_bfloat16* __restrict__ bmat,
        __hip_bfloat16* __restrict__ cs9b, float* __restrict__ part, float* __restrict__ hxT) {
    int s = blockIdx.x >> 5;
    int b = blockIdx.x & 31;
    int h = threadIdx.x;
    int tout0 = s * 64;
    int t0 = (s == 0) ? 0 : tout0 - 32;
    int t1 = tout0 + 64;
    float c[10] = {};
    float s9 = 0.f;
    float bt[10];
    {
        const __hip_bfloat16* bp = bmat + ((size_t)(t0 * B_DIM + b) * K_DIM) * H_DIM + h;
        #pragma unroll
        for (int k = 0; k < 10; ++k) bt[k] = __bfloat162float(bp[k * H_DIM]);
    }
    for (int t = t0; t < t1; ++t) {
        int tn = (t + 1 < t1) ? t + 1 : t;
        float btn[10];
        const __hip_bfloat16* bq = bmat + ((size_t)(tn * B_DIM + b) * K_DIM) * H_DIM + h;
        #pragma unroll
        for (int k = 0; k < 10; ++k) btn[k] = __bfloat162float(bq[k * H_DIM]);
        #pragma unroll
        for (int j = 9; j >= 1; --j) c[j] = 0.5f * c[j] + c[j - 1] * bt[j];
        c[0] = 0.5f * c[0] + bt[0];
        if (t >= tout0) {
            cs9b[(size_t)(t * B_DIM + b) * H_DIM + h] = __float2bfloat16(c[9]);
            s9 += c[9];
        }
        #pragma unroll
        for (int k = 0; k < 10; ++k) bt[k] = btn[k];
    }
    part[(size_t)(s * B_DIM + b) * H_DIM + h] = s9;
    if (s == 7) {
        float* hp = hxT + (size_t)(b * H_DIM + h) * K_DIM;
        #pragma unroll
        for (int k = 0; k < 10; ++k) hp[k] = c[k];
    }
}

__global__ __launch_bounds__(256) void recred_kernel(const float* __restrict__ part,
        float* __restrict__ mean9) {
    int i = blockIdx.x * 256 + threadIdx.x;            // 0..8191
    float s = 0.f;
    #pragma unroll
    for (int j = 0; j < 8; ++j) s += part[(size_t)j * 8192 + i];
    mean9[i] = s * (1.f / T_DIM);
}

// ---- single-workgroup lintrans: power iter + deflation + degree-3 Taylor, NO grid syncs ----
// lin = I - E/2 + 3/8 E^2 - 5/16 E^3 + (lam^{-1/2}-1) v v^T,  E = M - I - (lam-1) v v^T
// E held bf16 in LDS with XOR swizzle; E^2 via global round-trip (same-CU L1 coherence).
__global__ __launch_bounds__(512) void lintrans_one(
        const float* __restrict__ Mm, const float* __restrict__ rsum,
        float* __restrict__ Eg, float* __restrict__ E2g, __hip_bfloat16* __restrict__ e2b,
        float* __restrict__ lin, __hip_bfloat16* __restrict__ linb) {
    __shared__ __hip_bfloat16 Eb[65536];   // 128 KB, row-swizzled
    __shared__ float vv[256];
    __shared__ float yv[256];
    __shared__ float red[512];
    __shared__ float lamS;

    int tid = threadIdx.x;
    int wid = tid >> 6, lane = tid & 63;

    // ---- power iteration (coalesced via symmetry: y[col] = sum_g M[g][col] v[g]) ----
    if (tid < 256) vv[tid] = rsum[tid];
    __syncthreads();
    for (int it = 0; it <= NPOW; ++it) {
        int col = tid & 255, q = tid >> 8;             // q in {0,1}, 128-row chunks
        const float* mp = Mm + (size_t)q * 128 * 256 + col;
        float p = 0.f;
        #pragma unroll 8
        for (int g = 0; g < 128; ++g) p = fmaf(mp[(size_t)g * 256], vv[q * 128 + g], p);
        red[tid] = p;
        __syncthreads();
        if (it < NPOW) {
            if (tid < 256) {
                float y = red[tid] + red[tid + 256];
                yv[tid] = y;
                red[tid] = y * y;
            }
            __syncthreads();
            #pragma unroll
            for (int st = 128; st > 0; st >>= 1) {
                if (tid < st) red[tid] += red[tid + st];
                __syncthreads();
            }
            float inv = rsqrtf(red[0]);
            if (tid < 256) vv[tid] = yv[tid] * inv;
            __syncthreads();
        } else {
            if (tid < 256) red[tid] = (red[tid] + red[tid + 256]) * vv[tid];  // Rayleigh
            __syncthreads();
            #pragma unroll
            for (int st = 128; st > 0; st >>= 1) {
                if (tid < st) red[tid] += red[tid + st];
                __syncthreads();
            }
            if (tid == 0) lamS = red[0];
            __syncthreads();
        }
    }
    float lam = lamS;
    float lm1 = lam - 1.f;
    float lfac = rsqrtf(lam) - 1.f;

    // ---- E = M - I - (lam-1) v v^T : fp32 to global, bf16 swizzled to LDS ----
    char* ebp = (char*)Eb;
    for (int i = tid; i < 65536; i += 512) {
        int r = i >> 8, c = i & 255;
        float e = Mm[i] - ((r == c) ? 1.f : 0.f) - lm1 * vv[r] * vv[c];
        Eg[i] = e;
        *(__hip_bfloat16*)(ebp + r * 512 + ((c * 2) ^ ((r & 7) << 4))) = __float2bfloat16(e);
    }
    __threadfence();
    __syncthreads();

    int rl = lane & 15;
    int seg8 = (lane >> 4) * 8;          // element offset within k-step
    int col_l = lane & 15;
    int rseg = (lane >> 4) * 4;

    // ---- MM1: E2 = E @ E (E symmetric; both operand frags from LDS), 2 passes of 8 waves ----
    #pragma unroll 1
    for (int p = 0; p < 2; ++p) {
        int tt = wid + p * 8;            // 16 tiles, 4x4
        int twr = tt >> 2, twc = tt & 3;
        f32x4 acc[4][4] = {};
        #pragma unroll 1
        for (int kb = 0; kb < 256; kb += 32) {
            short8 a[4], b[4];
            #pragma unroll
            for (int m = 0; m < 4; ++m) {
                int row = twr * 64 + m * 16 + rl;
                a[m] = *(const short8*)(ebp + row * 512 + (((kb + seg8) * 2) ^ ((row & 7) << 4)));
            }
            #pragma unroll
            for (int n = 0; n < 4; ++n) {
                int row = twc * 64 + n * 16 + rl;
                b[n] = *(const short8*)(ebp + row * 512 + (((kb + seg8) * 2) ^ ((row & 7) << 4)));
            }
            #pragma unroll
            for (int m = 0; m < 4; ++m)
                #pragma unroll
                for (int n = 0; n < 4; ++n)
                    acc[m][n] = __builtin_amdgcn_mfma_f32_16x16x32_bf16(a[m], b[n], acc[m][n], 0, 0, 0);
        }
        #pragma unroll
        for (int m = 0; m < 4; ++m) {
            int rbase = twr * 64 + m * 16 + rseg;
            #pragma unroll
            for (int n = 0; n < 4; ++n) {
                int col = twc * 64 + n * 16 + col_l;
                #pragma unroll
                for (int j = 0; j < 4; ++j) {
                    float v2 = acc[m][n][j];
                    E2g[(size_t)(rbase + j) * 256 + col] = v2;
                    e2b[(size_t)(rbase + j) * 256 + col] = __float2bfloat16(v2);
                }
            }
        }
    }
    __threadfence();
    __syncthreads();

    // ---- MM2: E3 = E @ E2 (A frags from LDS E, B frags = rows of E2 from global bf16),
    //      fused epilogue: lin = I - E/2 + 3/8 E2 - 5/16 E3 + lfac v v^T ----
    #pragma unroll 1
    for (int p = 0; p < 2; ++p) {
        int tt = wid + p * 8;
        int twr = tt >> 2, twc = tt & 3;
        f32x4 acc[4][4] = {};
        #pragma unroll 1
        for (int kb = 0; kb < 256; kb += 32) {
            short8 a[4], b[4];
            #pragma unroll
            for (int m = 0; m < 4; ++m) {
                int row = twr * 64 + m * 16 + rl;
                a[m] = *(const short8*)(ebp + row * 512 + (((kb + seg8) * 2) ^ ((row & 7) << 4)));
            }
            #pragma unroll
            for (int n = 0; n < 4; ++n) {
                int row = twc * 64 + n * 16 + rl;
                b[n] = *(const short8*)(e2b + (size_t)row * 256 + kb + seg8);
            }
            #pragma unroll
            for (int m = 0; m < 4; ++m)
                #pragma unroll
                for (int n = 0; n < 4; ++n)
                    acc[m][n] = __builtin_amdgcn_mfma_f32_16x16x32_bf16(a[m], b[n], acc[m][n], 0, 0, 0);
        }
        #pragma unroll
        for (int m = 0; m < 4; ++m) {
            int rbase = twr * 64 + m * 16 + rseg;
            #pragma unroll
            for (int n = 0; n < 4; ++n) {
                int col = twc * 64 + n * 16 + col_l;
                #pragma unroll
                for (int j = 0; j < 4; ++j) {
                    int r = rbase + j;
                    size_t idx = (size_t)r * 256 + col;
                    float lv = ((r == col) ? 1.f : 0.f)
                             - 0.5f * Eg[idx] + 0.375f * E2g[idx] - 0.3125f * acc[m][n][j]
                             + lfac * vv[r] * vv[col];
                    lin[idx] = lv;
                    linb[idx] = __float2bfloat16(lv);
                }
            }
        }
    }
}

// ---- out0[b][g] = sum_h mean9[b][h] * lin[h][g] ----
__global__ __launch_bounds__(256) void outmean_kernel(const float* __restrict__ mean9,
        const float* __restrict__ lin, float* __restrict__ out) {
    int b = blockIdx.x, g = threadIdx.x;
    float acc = 0.f;
    const float* mrow = mean9 + b * H_DIM;
    #pragma unroll 8
    for (int h = 0; h < H_DIM; ++h) acc = fmaf(mrow[h], lin[(size_t)h * H_DIM + g], acc);
    out[b * H_DIM + g] = acc;
}

// ---- out1 = cs9b @ linb via bf16 MFMA (lin symmetric -> row-major linb is B^T form) ----
__global__ __launch_bounds__(256) void mm_out1_mfma(const __hip_bfloat16* __restrict__ A,
        const __hip_bfloat16* __restrict__ Bt, float* __restrict__ C) {
    __shared__ __hip_bfloat16 As[4096];   // [128][32]
    __shared__ __hip_bfloat16 Bs[4096];
    int tid = threadIdx.x;
    int wid = tid >> 6, lane = tid & 63;
    int m0 = blockIdx.x * 128, n0 = blockIdx.y * 128;
    int wr = wid >> 1, wc = wid & 1;
    int srow = tid >> 2;
    int scol = (tid & 3) * 8;
    f32x4 acc[4][4] = {};

    for (int kb = 0; kb < 256; kb += 32) {
        #pragma unroll
        for (int half = 0; half < 2; ++half) {
            const __hip_bfloat16* ga = A + (size_t)(m0 + half * 64 + srow) * 256 + kb + scol;
            const __hip_bfloat16* gb = Bt + (size_t)(n0 + half * 64 + srow) * 256 + kb + scol;
            __builtin_amdgcn_global_load_lds((const GLOBAL_AS void*)ga,
                (LDS_AS void*)(As + half * 2048 + wid * 512), 16, 0, 0);
            __builtin_amdgcn_global_load_lds((const GLOBAL_AS void*)gb,
                (LDS_AS void*)(Bs + half * 2048 + wid * 512), 16, 0, 0);
        }
        __syncthreads();
        int seg = (lane >> 4) * 8;
        int rl = lane & 15;
        short8 a[4], b[4];
        #pragma unroll
        for (int m = 0; m < 4; ++m)
            a[m] = *(const short8*)(As + (wr * 64 + m * 16 + rl) * 32 + seg);
        #pragma unroll
        for (int n = 0; n < 4; ++n)
            b[n] = *(const short8*)(Bs + (wc * 64 + n * 16 + rl) * 32 + seg);
        #pragma unroll
        for (int m = 0; m < 4; ++m)
            #pragma unroll
            for (int n = 0; n < 4; ++n)
                acc[m][n] = __builtin_amdgcn_mfma_f32_16x16x32_bf16(a[m], b[n], acc[m][n], 0, 0, 0);
        __syncthreads();
    }

    int col_l = lane & 15;
    int rseg = (lane >> 4) * 4;
    #pragma unroll
    for (int m = 0; m < 4; ++m) {
        int rbase = m0 + wr * 64 + m * 16 + rseg;
        #pragma unroll
        for (int n = 0; n < 4; ++n) {
            int col = n0 + wc * 64 + n * 16 + col_l;
            #pragma unroll
            for (int j = 0; j < 4; ++j)
                C[(size_t)(rbase + j) * 256 + col] = acc[m][n][j];
        }
    }
}

extern "C" void kernel_launch(void* const* d_in, const int* in_sizes, int n_in,
                              void* d_out, int out_size, void* d_ws, size_t ws_size,
                              hipStream_t stream) {
    const float* x = (const float*)d_in[0];
    const float* w = (const float*)d_in[1];
    float* out0 = (float*)d_out;                       // B*H
    float* out1 = out0 + (size_t)B_DIM * H_DIM;        // T*B*H
    float* hxT  = out1 + (size_t)TB * H_DIM;           // B*H*K

    char* ws = (char*)d_ws;
    __hip_bfloat16* wb   = (__hip_bfloat16*)(ws + 0);          // 1,310,720
    __hip_bfloat16* wb2  = (__hip_bfloat16*)(ws + 1310720);    // 1,310,720
    float* xninfo        = (float*)(ws + 2621440);             //   131,072
    float* Mm            = (float*)(ws + 2752512);             //   262,144
    float* rsum          = (float*)(ws + 3014656);             //     1,024
    float* Eg            = (float*)(ws + 3015680);             //   262,144
    float* E2g           = (float*)(ws + 3277824);             //   262,144
    __hip_bfloat16* e2b  = (__hip_bfloat16*)(ws + 3539968);    //   131,072
    float* lin           = (float*)(ws + 3671040);             //   262,144
    __hip_bfloat16* linb = (__hip_bfloat16*)(ws + 3933184);    //   131,072
    float* mean9         = (float*)(ws + 4064256);             //    32,768
    float* part          = (float*)(ws + 4097024);             //   262,144
    __hip_bfloat16* cs9b = (__hip_bfloat16*)(ws + 4359168);    // 8,388,608
    __hip_bfloat16* xb   = (__hip_bfloat16*)(ws + 12747776);   // 8,388,608
    __hip_bfloat16* bmat = (__hip_bfloat16*)(ws + 21136384);   // 83,886,080 -> ~100.2 MB

    hipMemsetAsync(rsum, 0, H_DIM * sizeof(float), stream);
    wnorm_kernel<<<dim3(640), dim3(256), 0, stream>>>(w, wb, wb2);
    xnorm_kernel<<<dim3(4096), dim3(256), 0, stream>>>(x, xninfo, xb);
    gemm_b_mfma<<<dim3(128, 20), dim3(256), 0, stream>>>(xb, wb, xninfo, bmat);
    gram_mfma<<<dim3(2, 2), dim3(256), 0, stream>>>(wb2, Mm, rsum);
    rec_kernel<<<dim3(256), dim3(256), 0, stream>>>(bmat, cs9b, part, hxT);
    recred_kernel<<<dim3(32), dim3(256), 0, stream>>>(part, mean9);
    lintrans_one<<<dim3(1), dim3(512), 0, stream>>>(Mm, rsum, Eg, E2g, e2b, lin, linb);
    outmean_kernel<<<dim3(32), dim3(256), 0, stream>>>(mean9, lin, out0);
    mm_out1_mfma<<<dim3(128, 2), dim3(256), 0, stream>>>(cs9b, linb, out1);
}

// Round 6
// 204.633 us; speedup vs baseline: 3.6352x; 1.1688x over previous
//
#include <hip/hip_runtime.h>
#include <hip/hip_bf16.h>

// Problem dims
#define T_DIM 512
#define B_DIM 32
#define IN_DIM 256
#define H_DIM 256
#define K_DIM 10
#define TB 16384          // T*B
#define NKH 2560          // H*K
#define NPOW 3            // normalized power updates (v0 = rsum = M@1 is already 1 step)

typedef __attribute__((ext_vector_type(8))) short short8;
typedef __attribute__((ext_vector_type(4))) float f32x4;

#define GLOBAL_AS __attribute__((address_space(1)))
#define LDS_AS __attribute__((address_space(3)))

__device__ __forceinline__ float wave_sum64(float v) {
    #pragma unroll
    for (int off = 32; off > 0; off >>= 1) v += __shfl_xor(v, off, 64);
    return v;
}

// ---- weight normalize: wb bf16 [(k*256+h)][256] (for gemm_b), wb2 bf16 [h][k*256+i] (for gram)
__global__ __launch_bounds__(256) void wnorm_kernel(const float* __restrict__ w,
        __hip_bfloat16* __restrict__ wb, __hip_bfloat16* __restrict__ wb2) {
    int wv = threadIdx.x >> 6, lane = threadIdx.x & 63;
    int row = blockIdx.x * 4 + wv;                     // 0..2559  (= h*10+k)
    const float* src = w + (size_t)row * IN_DIM;
    float v[4]; float s = 0.f;
    #pragma unroll
    for (int j = 0; j < 4; ++j) { v[j] = src[lane + 64 * j]; s += v[j] * v[j]; }
    s = wave_sum64(s);
    float inv = 1.f / fmaxf(sqrtf(s), 1e-4f);
    int h = row / K_DIM, k = row % K_DIM;
    __hip_bfloat16* d1 = wb + (size_t)(k * H_DIM + h) * IN_DIM;
    __hip_bfloat16* d2 = wb2 + (size_t)h * NKH + k * IN_DIM;
    #pragma unroll
    for (int j = 0; j < 4; ++j) {
        __hip_bfloat16 t = __float2bfloat16(v[j] * inv);
        d1[lane + 64 * j] = t;
        d2[lane + 64 * j] = t;
    }
}

// ---- x row norms + bf16 copy; xninfo[2r]=norm, xninfo[2r+1]=1/max(norm,eps)
__global__ __launch_bounds__(256) void xnorm_kernel(const float* __restrict__ x,
        float* __restrict__ xninfo, __hip_bfloat16* __restrict__ xb) {
    int wv = threadIdx.x >> 6, lane = threadIdx.x & 63;
    int row = blockIdx.x * 4 + wv;                     // 0..16383
    const float* src = x + (size_t)row * IN_DIM;
    float v[4]; float s = 0.f;
    #pragma unroll
    for (int j = 0; j < 4; ++j) { v[j] = src[lane + 64 * j]; s += v[j] * v[j]; }
    s = wave_sum64(s);
    float nrm = sqrtf(s);
    if (lane == 0) { xninfo[2 * row] = nrm; xninfo[2 * row + 1] = 1.f / fmaxf(nrm, 1e-4f); }
    __hip_bfloat16* d = xb + (size_t)row * IN_DIM;
    #pragma unroll
    for (int j = 0; j < 4; ++j) d[lane + 64 * j] = __float2bfloat16(v[j]);
}

// ---- big GEMM via bf16 MFMA + kappa epilogue -> bmat bf16 [t][b][k][h] ----
__global__ __launch_bounds__(256) void gemm_b_mfma(const __hip_bfloat16* __restrict__ xb,
        const __hip_bfloat16* __restrict__ wb, const float* __restrict__ xninfo,
        __hip_bfloat16* __restrict__ bmat) {
    __shared__ __hip_bfloat16 As[4096];   // [128][32]
    __shared__ __hip_bfloat16 Bs[4096];
    int tid = threadIdx.x;
    int wid = tid >> 6, lane = tid & 63;
    int m0 = blockIdx.x * 128, n0 = blockIdx.y * 128;
    int wr = wid >> 1, wc = wid & 1;
    int srow = tid >> 2;
    int scol = (tid & 3) * 8;
    f32x4 acc[4][4] = {};

    for (int kb = 0; kb < IN_DIM; kb += 32) {
        #pragma unroll
        for (int half = 0; half < 2; ++half) {
            const __hip_bfloat16* ga = xb + (size_t)(m0 + half * 64 + srow) * IN_DIM + kb + scol;
            const __hip_bfloat16* gb = wb + (size_t)(n0 + half * 64 + srow) * IN_DIM + kb + scol;
            __builtin_amdgcn_global_load_lds((const GLOBAL_AS void*)ga,
                (LDS_AS void*)(As + half * 2048 + wid * 512), 16, 0, 0);
            __builtin_amdgcn_global_load_lds((const GLOBAL_AS void*)gb,
                (LDS_AS void*)(Bs + half * 2048 + wid * 512), 16, 0, 0);
        }
        __syncthreads();
        int seg = (lane >> 4) * 8;
        int rl = lane & 15;
        short8 a[4], b[4];
        #pragma unroll
        for (int m = 0; m < 4; ++m)
            a[m] = *(const short8*)(As + (wr * 64 + m * 16 + rl) * 32 + seg);
        #pragma unroll
        for (int n = 0; n < 4; ++n)
            b[n] = *(const short8*)(Bs + (wc * 64 + n * 16 + rl) * 32 + seg);
        #pragma unroll
        for (int m = 0; m < 4; ++m)
            #pragma unroll
            for (int n = 0; n < 4; ++n)
                acc[m][n] = __builtin_amdgcn_mfma_f32_16x16x32_bf16(a[m], b[n], acc[m][n], 0, 0, 0);
        __syncthreads();
    }

    int kk = blockIdx.y >> 1;
    int col_l = lane & 15;
    int rseg = (lane >> 4) * 4;
    #pragma unroll
    for (int m = 0; m < 4; ++m) {
        int rbase = m0 + wr * 64 + m * 16 + rseg;
        float4 q0 = *(const float4*)(xninfo + 2 * rbase);
        float4 q1 = *(const float4*)(xninfo + 2 * rbase + 4);
        float nrm[4] = { q0.x, q0.z, q1.x, q1.z };
        float inv[4] = { q0.y, q0.w, q1.y, q1.w };
        #pragma unroll
        for (int n = 0; n < 4; ++n) {
            int col = n0 + wc * 64 + n * 16 + col_l;
            int h = col & 255;
            #pragma unroll
            for (int j = 0; j < 4; ++j) {
                float bv = nrm[j] * __expf(0.4f * acc[m][n][j] * inv[j] - 0.4f);
                bmat[((size_t)(rbase + j) * K_DIM + kk) * H_DIM + h] = __float2bfloat16(bv);
            }
        }
    }
}

// ---- Gram via bf16 MFMA: M[h][g] = exp(0.4*dot(wb2[h],wb2[g]) - 4); rsum += row sums ----
__global__ __launch_bounds__(256) void gram_mfma(const __hip_bfloat16* __restrict__ wb2,
        float* __restrict__ Mm, float* __restrict__ rsum) {
    __shared__ __hip_bfloat16 As[4096];   // [128][32]
    __shared__ __hip_bfloat16 Bs[4096];
    int tid = threadIdx.x;
    int wid = tid >> 6, lane = tid & 63;
    int m0 = blockIdx.x * 128, n0 = blockIdx.y * 128;
    int wr = wid >> 1, wc = wid & 1;
    int srow = tid >> 2;
    int scol = (tid & 3) * 8;
    f32x4 acc[4][4] = {};

    for (int kb = 0; kb < NKH; kb += 32) {
        #pragma unroll
        for (int half = 0; half < 2; ++half) {
            const __hip_bfloat16* ga = wb2 + (size_t)(m0 + half * 64 + srow) * NKH + kb + scol;
            const __hip_bfloat16* gb = wb2 + (size_t)(n0 + half * 64 + srow) * NKH + kb + scol;
            __builtin_amdgcn_global_load_lds((const GLOBAL_AS void*)ga,
                (LDS_AS void*)(As + half * 2048 + wid * 512), 16, 0, 0);
            __builtin_amdgcn_global_load_lds((const GLOBAL_AS void*)gb,
                (LDS_AS void*)(Bs + half * 2048 + wid * 512), 16, 0, 0);
        }
        __syncthreads();
        int seg = (lane >> 4) * 8;
        int rl = lane & 15;
        short8 a[4], b[4];
        #pragma unroll
        for (int m = 0; m < 4; ++m)
            a[m] = *(const short8*)(As + (wr * 64 + m * 16 + rl) * 32 + seg);
        #pragma unroll
        for (int n = 0; n < 4; ++n)
            b[n] = *(const short8*)(Bs + (wc * 64 + n * 16 + rl) * 32 + seg);
        #pragma unroll
        for (int m = 0; m < 4; ++m)
            #pragma unroll
            for (int n = 0; n < 4; ++n)
                acc[m][n] = __builtin_amdgcn_mfma_f32_16x16x32_bf16(a[m], b[n], acc[m][n], 0, 0, 0);
        __syncthreads();
    }

    int col_l = lane & 15;
    int rseg = (lane >> 4) * 4;
    float rpart[4][4];
    #pragma unroll
    for (int m = 0; m < 4; ++m) {
        int rbase = m0 + wr * 64 + m * 16 + rseg;
        #pragma unroll
        for (int j = 0; j < 4; ++j) rpart[m][j] = 0.f;
        #pragma unroll
        for (int n = 0; n < 4; ++n) {
            int col = n0 + wc * 64 + n * 16 + col_l;
            #pragma unroll
            for (int j = 0; j < 4; ++j) {
                float e = __expf(0.4f * acc[m][n][j] - 4.0f);
                Mm[(size_t)(rbase + j) * H_DIM + col] = e;
                rpart[m][j] += e;
            }
        }
    }
    #pragma unroll
    for (int off = 1; off < 16; off <<= 1)
        #pragma unroll
        for (int m = 0; m < 4; ++m)
            #pragma unroll
            for (int j = 0; j < 4; ++j)
                rpart[m][j] += __shfl_xor(rpart[m][j], off, 64);
    if (col_l == 0) {
        #pragma unroll
        for (int m = 0; m < 4; ++m) {
            int rbase = m0 + wr * 64 + m * 16 + rseg;
            #pragma unroll
            for (int j = 0; j < 4; ++j)
                atomicAdd(&rsum[rbase + j], rpart[m][j]);
        }
    }
}

// ---- recurrence with warm-up chunks (warm-up 32: 0.5^32 ~ 2e-10 init error) ----
__global__ __launch_bounds__(256) void rec_kernel(const __hip_bfloat16* __restrict__ bmat,
        __hip_bfloat16* __restrict__ cs9b, float* __restrict__ part, float* __restrict__ hxT) {
    int s = blockIdx.x >> 5;
    int b = blockIdx.x & 31;
    int h = threadIdx.x;
    int tout0 = s * 64;
    int t0 = (s == 0) ? 0 : tout0 - 32;
    int t1 = tout0 + 64;
    float c[10] = {};
    float s9 = 0.f;
    float bt[10];
    {
        const __hip_bfloat16* bp = bmat + ((size_t)(t0 * B_DIM + b) * K_DIM) * H_DIM + h;
        #pragma unroll
        for (int k = 0; k < 10; ++k) bt[k] = __bfloat162float(bp[k * H_DIM]);
    }
    for (int t = t0; t < t1; ++t) {
        int tn = (t + 1 < t1) ? t + 1 : t;
        float btn[10];
        const __hip_bfloat16* bq = bmat + ((size_t)(tn * B_DIM + b) * K_DIM) * H_DIM + h;
        #pragma unroll
        for (int k = 0; k < 10; ++k) btn[k] = __bfloat162float(bq[k * H_DIM]);
        #pragma unroll
        for (int j = 9; j >= 1; --j) c[j] = 0.5f * c[j] + c[j - 1] * bt[j];
        c[0] = 0.5f * c[0] + bt[0];
        if (t >= tout0) {
            cs9b[(size_t)(t * B_DIM + b) * H_DIM + h] = __float2bfloat16(c[9]);
            s9 += c[9];
        }
        #pragma unroll
        for (int k = 0; k < 10; ++k) bt[k] = btn[k];
    }
    part[(size_t)(s * B_DIM + b) * H_DIM + h] = s9;
    if (s == 7) {
        float* hp = hxT + (size_t)(b * H_DIM + h) * K_DIM;
        #pragma unroll
        for (int k = 0; k < 10; ++k) hp[k] = c[k];
    }
}

__global__ __launch_bounds__(256) void recred_kernel(const float* __restrict__ part,
        float* __restrict__ mean9) {
    int i = blockIdx.x * 256 + threadIdx.x;            // 0..8191
    float s = 0.f;
    #pragma unroll
    for (int j = 0; j < 8; ++j) s += part[(size_t)j * 8192 + i];
    mean9[i] = s * (1.f / T_DIM);
}

// ---- P1: power iteration (1 block): vbuf = Perron vector, cbuf = {lam, lam-1, rsqrt(lam)-1}
__global__ __launch_bounds__(512) void power_kernel(const float* __restrict__ Mm,
        const float* __restrict__ rsum, float* __restrict__ vbuf, float* __restrict__ cbuf) {
    __shared__ float vv[256];
    __shared__ float yv[256];
    __shared__ float red[512];
    int tid = threadIdx.x;
    if (tid < 256) vv[tid] = rsum[tid];
    __syncthreads();
    for (int it = 0; it <= NPOW; ++it) {
        int col = tid & 255, q = tid >> 8;             // q in {0,1}: 128-row chunks
        const float* mp = Mm + (size_t)q * 128 * 256 + col;
        float p = 0.f;
        #pragma unroll 8
        for (int g = 0; g < 128; ++g) p = fmaf(mp[(size_t)g * 256], vv[q * 128 + g], p);
        red[tid] = p;
        __syncthreads();
        if (it < NPOW) {
            if (tid < 256) {
                float y = red[tid] + red[tid + 256];
                yv[tid] = y;
                red[tid] = y * y;
            }
            __syncthreads();
            #pragma unroll
            for (int st = 128; st > 0; st >>= 1) {
                if (tid < st) red[tid] += red[tid + st];
                __syncthreads();
            }
            float inv = rsqrtf(red[0]);
            if (tid < 256) vv[tid] = yv[tid] * inv;
            __syncthreads();
        } else {
            if (tid < 256) red[tid] = (red[tid] + red[tid + 256]) * vv[tid];  // Rayleigh
            __syncthreads();
            #pragma unroll
            for (int st = 128; st > 0; st >>= 1) {
                if (tid < st) red[tid] += red[tid + st];
                __syncthreads();
            }
            if (tid == 0) {
                float lam = red[0];
                cbuf[0] = lam;
                cbuf[1] = lam - 1.f;
                cbuf[2] = rsqrtf(lam) - 1.f;
            }
        }
    }
    if (tid < 256) vbuf[tid] = vv[tid];
}

// ---- P2: E2 = E @ E, tiled 64x64 over 16 blocks. E rows recomputed from Mm on the fly. ----
__global__ __launch_bounds__(256) void e2_kernel(const float* __restrict__ Mm,
        const float* __restrict__ vbuf, const float* __restrict__ cbuf,
        float* __restrict__ E2g, __hip_bfloat16* __restrict__ e2b) {
    __shared__ __hip_bfloat16 EA[16384];   // [64][256] bf16, row-swizzled
    __shared__ __hip_bfloat16 EC[16384];
    __shared__ float vv[256];
    int tid = threadIdx.x;
    int r0 = (blockIdx.x >> 2) * 64, c0 = (blockIdx.x & 3) * 64;
    float lm1 = cbuf[1];
    if (tid < 256) vv[tid] = vbuf[tid];
    __syncthreads();
    char* pa = (char*)EA;
    char* pc = (char*)EC;
    // stage E rows r0.. and c0.. as bf16 swizzled
    for (int f = tid; f < 4096; f += 256) {
        int row = f >> 6, c4 = (f & 63) << 2;
        {
            int r = r0 + row;
            float4 mv = *(const float4*)(Mm + (size_t)r * 256 + c4);
            float vr = lm1 * vv[r];
            __hip_bfloat16 hb[4];
            hb[0] = __float2bfloat16(mv.x - ((r == c4 + 0) ? 1.f : 0.f) - vr * vv[c4 + 0]);
            hb[1] = __float2bfloat16(mv.y - ((r == c4 + 1) ? 1.f : 0.f) - vr * vv[c4 + 1]);
            hb[2] = __float2bfloat16(mv.z - ((r == c4 + 2) ? 1.f : 0.f) - vr * vv[c4 + 2]);
            hb[3] = __float2bfloat16(mv.w - ((r == c4 + 3) ? 1.f : 0.f) - vr * vv[c4 + 3]);
            *(short4*)(pa + row * 512 + ((c4 * 2) ^ ((row & 7) << 4))) = *(short4*)hb;
        }
        {
            int r = c0 + row;
            float4 mv = *(const float4*)(Mm + (size_t)r * 256 + c4);
            float vr = lm1 * vv[r];
            __hip_bfloat16 hb[4];
            hb[0] = __float2bfloat16(mv.x - ((r == c4 + 0) ? 1.f : 0.f) - vr * vv[c4 + 0]);
            hb[1] = __float2bfloat16(mv.y - ((r == c4 + 1) ? 1.f : 0.f) - vr * vv[c4 + 1]);
            hb[2] = __float2bfloat16(mv.z - ((r == c4 + 2) ? 1.f : 0.f) - vr * vv[c4 + 2]);
            hb[3] = __float2bfloat16(mv.w - ((r == c4 + 3) ? 1.f : 0.f) - vr * vv[c4 + 3]);
            *(short4*)(pc + row * 512 + ((c4 * 2) ^ ((row & 7) << 4))) = *(short4*)hb;
        }
    }
    __syncthreads();
    int wv = tid >> 6, lane = tid & 63;
    int rl = lane & 15, seg8 = (lane >> 4) * 8;
    f32x4 acc[4] = {};
    for (int kb = 0; kb < 256; kb += 32) {
        int row = wv * 16 + rl;
        short8 a = *(const short8*)(pa + row * 512 + (((kb + seg8) * 2) ^ ((rl & 7) << 4)));
        short8 b[4];
        #pragma unroll
        for (int n = 0; n < 4; ++n) {
            int rowb = n * 16 + rl;
            b[n] = *(const short8*)(pc + rowb * 512 + (((kb + seg8) * 2) ^ ((rl & 7) << 4)));
        }
        #pragma unroll
        for (int n = 0; n < 4; ++n)
            acc[n] = __builtin_amdgcn_mfma_f32_16x16x32_bf16(a, b[n], acc[n], 0, 0, 0);
    }
    int col_l = lane & 15, rseg = (lane >> 4) * 4;
    #pragma unroll
    for (int n = 0; n < 4; ++n) {
        #pragma unroll
        for (int j = 0; j < 4; ++j) {
            int r = r0 + wv * 16 + rseg + j;
            int c = c0 + n * 16 + col_l;
            size_t idx = (size_t)r * 256 + c;
            E2g[idx] = acc[n][j];
            e2b[idx] = __float2bfloat16(acc[n][j]);
        }
    }
}

// ---- P3: E3 = E @ E2; fused lin = 1.5I - Mm/2 + (lm1/2+lfac) vv^T + 3/8 E2 - 5/16 E3 ----
__global__ __launch_bounds__(256) void e3lin_kernel(const float* __restrict__ Mm,
        const float* __restrict__ vbuf, const float* __restrict__ cbuf,
        const float* __restrict__ E2g, const __hip_bfloat16* __restrict__ e2b,
        float* __restrict__ lin, __hip_bfloat16* __restrict__ linb) {
    __shared__ __hip_bfloat16 EA[16384];   // [64][256] E rows, swizzled
    __shared__ __hip_bfloat16 EC[16384];   // [64][256] E2 rows (=cols, symmetric), swizzled
    __shared__ float vv[256];
    int tid = threadIdx.x;
    int r0 = (blockIdx.x >> 2) * 64, c0 = (blockIdx.x & 3) * 64;
    float lm1 = cbuf[1];
    float wfac = 0.5f * cbuf[1] + cbuf[2];
    if (tid < 256) vv[tid] = vbuf[tid];
    __syncthreads();
    char* pa = (char*)EA;
    char* pc = (char*)EC;
    for (int f = tid; f < 4096; f += 256) {
        int row = f >> 6, c4 = (f & 63) << 2;
        int r = r0 + row;
        float4 mv = *(const float4*)(Mm + (size_t)r * 256 + c4);
        float vr = lm1 * vv[r];
        __hip_bfloat16 hb[4];
        hb[0] = __float2bfloat16(mv.x - ((r == c4 + 0) ? 1.f : 0.f) - vr * vv[c4 + 0]);
        hb[1] = __float2bfloat16(mv.y - ((r == c4 + 1) ? 1.f : 0.f) - vr * vv[c4 + 1]);
        hb[2] = __float2bfloat16(mv.z - ((r == c4 + 2) ? 1.f : 0.f) - vr * vv[c4 + 2]);
        hb[3] = __float2bfloat16(mv.w - ((r == c4 + 3) ? 1.f : 0.f) - vr * vv[c4 + 3]);
        *(short4*)(pa + row * 512 + ((c4 * 2) ^ ((row & 7) << 4))) = *(short4*)hb;
    }
    for (int f = tid; f < 2048; f += 256) {
        int row = f >> 5, c8 = (f & 31) << 3;
        short8 v8 = *(const short8*)(e2b + (size_t)(c0 + row) * 256 + c8);
        *(short8*)(pc + row * 512 + ((c8 * 2) ^ ((row & 7) << 4))) = v8;
    }
    __syncthreads();
    int wv = tid >> 6, lane = tid & 63;
    int rl = lane & 15, seg8 = (lane >> 4) * 8;
    f32x4 acc[4] = {};
    for (int kb = 0; kb < 256; kb += 32) {
        int row = wv * 16 + rl;
        short8 a = *(const short8*)(pa + row * 512 + (((kb + seg8) * 2) ^ ((rl & 7) << 4)));
        short8 b[4];
        #pragma unroll
        for (int n = 0; n < 4; ++n) {
            int rowb = n * 16 + rl;
            b[n] = *(const short8*)(pc + rowb * 512 + (((kb + seg8) * 2) ^ ((rl & 7) << 4)));
        }
        #pragma unroll
        for (int n = 0; n < 4; ++n)
            acc[n] = __builtin_amdgcn_mfma_f32_16x16x32_bf16(a, b[n], acc[n], 0, 0, 0);
    }
    int col_l = lane & 15, rseg = (lane >> 4) * 4;
    #pragma unroll
    for (int n = 0; n < 4; ++n) {
        #pragma unroll
        for (int j = 0; j < 4; ++j) {
            int r = r0 + wv * 16 + rseg + j;
            int c = c0 + n * 16 + col_l;
            size_t idx = (size_t)r * 256 + c;
            float lv = ((r == c) ? 1.5f : 0.f) - 0.5f * Mm[idx] + wfac * vv[r] * vv[c]
                     + 0.375f * E2g[idx] - 0.3125f * acc[n][j];
            lin[idx] = lv;
            linb[idx] = __float2bfloat16(lv);
        }
    }
}

// ---- out0[b][g] = sum_h mean9[b][h] * lin[h][g] ----
__global__ __launch_bounds__(256) void outmean_kernel(const float* __restrict__ mean9,
        const float* __restrict__ lin, float* __restrict__ out) {
    int b = blockIdx.x, g = threadIdx.x;
    float acc = 0.f;
    const float* mrow = mean9 + b * H_DIM;
    #pragma unroll 8
    for (int h = 0; h < H_DIM; ++h) acc = fmaf(mrow[h], lin[(size_t)h * H_DIM + g], acc);
    out[b * H_DIM + g] = acc;
}

// ---- out1 = cs9b @ linb via bf16 MFMA (lin symmetric -> row-major linb is B^T form) ----
__global__ __launch_bounds__(256) void mm_out1_mfma(const __hip_bfloat16* __restrict__ A,
        const __hip_bfloat16* __restrict__ Bt, float* __restrict__ C) {
    __shared__ __hip_bfloat16 As[4096];   // [128][32]
    __shared__ __hip_bfloat16 Bs[4096];
    int tid = threadIdx.x;
    int wid = tid >> 6, lane = tid & 63;
    int m0 = blockIdx.x * 128, n0 = blockIdx.y * 128;
    int wr = wid >> 1, wc = wid & 1;
    int srow = tid >> 2;
    int scol = (tid & 3) * 8;
    f32x4 acc[4][4] = {};

    for (int kb = 0; kb < 256; kb += 32) {
        #pragma unroll
        for (int half = 0; half < 2; ++half) {
            const __hip_bfloat16* ga = A + (size_t)(m0 + half * 64 + srow) * 256 + kb + scol;
            const __hip_bfloat16* gb = Bt + (size_t)(n0 + half * 64 + srow) * 256 + kb + scol;
            __builtin_amdgcn_global_load_lds((const GLOBAL_AS void*)ga,
                (LDS_AS void*)(As + half * 2048 + wid * 512), 16, 0, 0);
            __builtin_amdgcn_global_load_lds((const GLOBAL_AS void*)gb,
                (LDS_AS void*)(Bs + half * 2048 + wid * 512), 16, 0, 0);
        }
        __syncthreads();
        int seg = (lane >> 4) * 8;
        int rl = lane & 15;
        short8 a[4], b[4];
        #pragma unroll
        for (int m = 0; m < 4; ++m)
            a[m] = *(const short8*)(As + (wr * 64 + m * 16 + rl) * 32 + seg);
        #pragma unroll
        for (int n = 0; n < 4; ++n)
            b[n] = *(const short8*)(Bs + (wc * 64 + n * 16 + rl) * 32 + seg);
        #pragma unroll
        for (int m = 0; m < 4; ++m)
            #pragma unroll
            for (int n = 0; n < 4; ++n)
                acc[m][n] = __builtin_amdgcn_mfma_f32_16x16x32_bf16(a[m], b[n], acc[m][n], 0, 0, 0);
        __syncthreads();
    }

    int col_l = lane & 15;
    int rseg = (lane >> 4) * 4;
    #pragma unroll
    for (int m = 0; m < 4; ++m) {
        int rbase = m0 + wr * 64 + m * 16 + rseg;
        #pragma unroll
        for (int n = 0; n < 4; ++n) {
            int col = n0 + wc * 64 + n * 16 + col_l;
            #pragma unroll
            for (int j = 0; j < 4; ++j)
                C[(size_t)(rbase + j) * 256 + col] = acc[m][n][j];
        }
    }
}

extern "C" void kernel_launch(void* const* d_in, const int* in_sizes, int n_in,
                              void* d_out, int out_size, void* d_ws, size_t ws_size,
                              hipStream_t stream) {
    const float* x = (const float*)d_in[0];
    const float* w = (const float*)d_in[1];
    float* out0 = (float*)d_out;                       // B*H
    float* out1 = out0 + (size_t)B_DIM * H_DIM;        // T*B*H
    float* hxT  = out1 + (size_t)TB * H_DIM;           // B*H*K

    char* ws = (char*)d_ws;
    __hip_bfloat16* wb   = (__hip_bfloat16*)(ws + 0);          // 1,310,720
    __hip_bfloat16* wb2  = (__hip_bfloat16*)(ws + 1310720);    // 1,310,720
    float* xninfo        = (float*)(ws + 2621440);             //   131,072
    float* Mm            = (float*)(ws + 2752512);             //   262,144
    float* rsum          = (float*)(ws + 3014656);             //     1,024
    float* E2g           = (float*)(ws + 3015680);             //   262,144
    __hip_bfloat16* e2b  = (__hip_bfloat16*)(ws + 3277824);    //   131,072
    float* lin           = (float*)(ws + 3408896);             //   262,144
    __hip_bfloat16* linb = (__hip_bfloat16*)(ws + 3671040);    //   131,072
    float* vbuf          = (float*)(ws + 3802112);             //     1,024
    float* cbuf          = (float*)(ws + 3803136);             //     1,024
    float* mean9         = (float*)(ws + 3804160);             //    32,768
    float* part          = (float*)(ws + 3836928);             //   262,144
    __hip_bfloat16* cs9b = (__hip_bfloat16*)(ws + 4099072);    // 8,388,608
    __hip_bfloat16* xb   = (__hip_bfloat16*)(ws + 12487680);   // 8,388,608
    __hip_bfloat16* bmat = (__hip_bfloat16*)(ws + 20876288);   // 83,886,080 -> ~99.9 MB

    hipMemsetAsync(rsum, 0, H_DIM * sizeof(float), stream);
    wnorm_kernel<<<dim3(640), dim3(256), 0, stream>>>(w, wb, wb2);
    xnorm_kernel<<<dim3(4096), dim3(256), 0, stream>>>(x, xninfo, xb);
    gemm_b_mfma<<<dim3(128, 20), dim3(256), 0, stream>>>(xb, wb, xninfo, bmat);
    gram_mfma<<<dim3(2, 2), dim3(256), 0, stream>>>(wb2, Mm, rsum);
    rec_kernel<<<dim3(256), dim3(256), 0, stream>>>(bmat, cs9b, part, hxT);
    recred_kernel<<<dim3(32), dim3(256), 0, stream>>>(part, mean9);
    power_kernel<<<dim3(1), dim3(512), 0, stream>>>(Mm, rsum, vbuf, cbuf);
    e2_kernel<<<dim3(16), dim3(256), 0, stream>>>(Mm, vbuf, cbuf, E2g, e2b);
    e3lin_kernel<<<dim3(16), dim3(256), 0, stream>>>(Mm, vbuf, cbuf, E2g, e2b, lin, linb);
    outmean_kernel<<<dim3(32), dim3(256), 0, stream>>>(mean9, lin, out0);
    mm_out1_mfma<<<dim3(128, 2), dim3(256), 0, stream>>>(cs9b, linb, out1);
}

// Round 7
// 156.801 us; speedup vs baseline: 4.7442x; 1.3051x over previous
//
#include <hip/hip_runtime.h>
#include <hip/hip_bf16.h>

// Problem dims
#define T_DIM 512
#define B_DIM 32
#define IN_DIM 256
#define H_DIM 256
#define K_DIM 10
#define TB 16384          // T*B
#define NKH 2560          // H*K
#define NPOW 3            // normalized power updates (v0 = rsum = M@1 is already 1 step)

typedef __attribute__((ext_vector_type(8))) short short8;
typedef __attribute__((ext_vector_type(4))) float f32x4;

#define GLOBAL_AS __attribute__((address_space(1)))
#define LDS_AS __attribute__((address_space(3)))

__device__ __forceinline__ float wave_sum64(float v) {
    #pragma unroll
    for (int off = 32; off > 0; off >>= 1) v += __shfl_xor(v, off, 64);
    return v;
}

// ---- weight normalize: wb bf16 [(k*256+h)][256] (for gemm_b), wb2 bf16 [h][k*256+i] (for gram)
__global__ __launch_bounds__(256) void wnorm_kernel(const float* __restrict__ w,
        __hip_bfloat16* __restrict__ wb, __hip_bfloat16* __restrict__ wb2) {
    int wv = threadIdx.x >> 6, lane = threadIdx.x & 63;
    int row = blockIdx.x * 4 + wv;                     // 0..2559  (= h*10+k)
    const float* src = w + (size_t)row * IN_DIM;
    float v[4]; float s = 0.f;
    #pragma unroll
    for (int j = 0; j < 4; ++j) { v[j] = src[lane + 64 * j]; s += v[j] * v[j]; }
    s = wave_sum64(s);
    float inv = 1.f / fmaxf(sqrtf(s), 1e-4f);
    int h = row / K_DIM, k = row % K_DIM;
    __hip_bfloat16* d1 = wb + (size_t)(k * H_DIM + h) * IN_DIM;
    __hip_bfloat16* d2 = wb2 + (size_t)h * NKH + k * IN_DIM;
    #pragma unroll
    for (int j = 0; j < 4; ++j) {
        __hip_bfloat16 t = __float2bfloat16(v[j] * inv);
        d1[lane + 64 * j] = t;
        d2[lane + 64 * j] = t;
    }
}

// ---- x row norms + bf16 copy; xninfo[2r]=norm, xninfo[2r+1]=1/max(norm,eps)
__global__ __launch_bounds__(256) void xnorm_kernel(const float* __restrict__ x,
        float* __restrict__ xninfo, __hip_bfloat16* __restrict__ xb) {
    int wv = threadIdx.x >> 6, lane = threadIdx.x & 63;
    int row = blockIdx.x * 4 + wv;                     // 0..16383
    const float* src = x + (size_t)row * IN_DIM;
    float v[4]; float s = 0.f;
    #pragma unroll
    for (int j = 0; j < 4; ++j) { v[j] = src[lane + 64 * j]; s += v[j] * v[j]; }
    s = wave_sum64(s);
    float nrm = sqrtf(s);
    if (lane == 0) { xninfo[2 * row] = nrm; xninfo[2 * row + 1] = 1.f / fmaxf(nrm, 1e-4f); }
    __hip_bfloat16* d = xb + (size_t)row * IN_DIM;
    #pragma unroll
    for (int j = 0; j < 4; ++j) d[lane + 64 * j] = __float2bfloat16(v[j]);
}

// ---- big GEMM via bf16 MFMA + kappa epilogue -> bmat bf16 [t][b][k][h] ----
__global__ __launch_bounds__(256) void gemm_b_mfma(const __hip_bfloat16* __restrict__ xb,
        const __hip_bfloat16* __restrict__ wb, const float* __restrict__ xninfo,
        __hip_bfloat16* __restrict__ bmat) {
    __shared__ __hip_bfloat16 As[4096];   // [128][32]
    __shared__ __hip_bfloat16 Bs[4096];
    int tid = threadIdx.x;
    int wid = tid >> 6, lane = tid & 63;
    int m0 = blockIdx.x * 128, n0 = blockIdx.y * 128;
    int wr = wid >> 1, wc = wid & 1;
    int srow = tid >> 2;
    int scol = (tid & 3) * 8;
    f32x4 acc[4][4] = {};

    for (int kb = 0; kb < IN_DIM; kb += 32) {
        #pragma unroll
        for (int half = 0; half < 2; ++half) {
            const __hip_bfloat16* ga = xb + (size_t)(m0 + half * 64 + srow) * IN_DIM + kb + scol;
            const __hip_bfloat16* gb = wb + (size_t)(n0 + half * 64 + srow) * IN_DIM + kb + scol;
            __builtin_amdgcn_global_load_lds((const GLOBAL_AS void*)ga,
                (LDS_AS void*)(As + half * 2048 + wid * 512), 16, 0, 0);
            __builtin_amdgcn_global_load_lds((const GLOBAL_AS void*)gb,
                (LDS_AS void*)(Bs + half * 2048 + wid * 512), 16, 0, 0);
        }
        __syncthreads();
        int seg = (lane >> 4) * 8;
        int rl = lane & 15;
        short8 a[4], b[4];
        #pragma unroll
        for (int m = 0; m < 4; ++m)
            a[m] = *(const short8*)(As + (wr * 64 + m * 16 + rl) * 32 + seg);
        #pragma unroll
        for (int n = 0; n < 4; ++n)
            b[n] = *(const short8*)(Bs + (wc * 64 + n * 16 + rl) * 32 + seg);
        #pragma unroll
        for (int m = 0; m < 4; ++m)
            #pragma unroll
            for (int n = 0; n < 4; ++n)
                acc[m][n] = __builtin_amdgcn_mfma_f32_16x16x32_bf16(a[m], b[n], acc[m][n], 0, 0, 0);
        __syncthreads();
    }

    int kk = blockIdx.y >> 1;
    int col_l = lane & 15;
    int rseg = (lane >> 4) * 4;
    #pragma unroll
    for (int m = 0; m < 4; ++m) {
        int rbase = m0 + wr * 64 + m * 16 + rseg;
        float4 q0 = *(const float4*)(xninfo + 2 * rbase);
        float4 q1 = *(const float4*)(xninfo + 2 * rbase + 4);
        float nrm[4] = { q0.x, q0.z, q1.x, q1.z };
        float inv[4] = { q0.y, q0.w, q1.y, q1.w };
        #pragma unroll
        for (int n = 0; n < 4; ++n) {
            int col = n0 + wc * 64 + n * 16 + col_l;
            int h = col & 255;
            #pragma unroll
            for (int j = 0; j < 4; ++j) {
                float bv = nrm[j] * __expf(0.4f * acc[m][n][j] * inv[j] - 0.4f);
                bmat[((size_t)(rbase + j) * K_DIM + kk) * H_DIM + h] = __float2bfloat16(bv);
            }
        }
    }
}

// ---- Gram split-K partial: Mpart[kz] = wb2[:,kz*160:(kz+1)*160] @ wb2^T (128x128 tile) ----
__global__ __launch_bounds__(256) void gram_partial(const __hip_bfloat16* __restrict__ wb2,
        float* __restrict__ Mpart) {
    __shared__ __hip_bfloat16 As[4096];   // [128][32]
    __shared__ __hip_bfloat16 Bs[4096];
    int tid = threadIdx.x;
    int wid = tid >> 6, lane = tid & 63;
    int m0 = blockIdx.x * 128, n0 = blockIdx.y * 128;
    int kz = blockIdx.z;                  // 0..15, chunk of 160 = 5 steps of 32
    int wr = wid >> 1, wc = wid & 1;
    int srow = tid >> 2;
    int scol = (tid & 3) * 8;
    f32x4 acc[4][4] = {};

    for (int ks = 0; ks < 5; ++ks) {
        int kb = kz * 160 + ks * 32;
        #pragma unroll
        for (int half = 0; half < 2; ++half) {
            const __hip_bfloat16* ga = wb2 + (size_t)(m0 + half * 64 + srow) * NKH + kb + scol;
            const __hip_bfloat16* gb = wb2 + (size_t)(n0 + half * 64 + srow) * NKH + kb + scol;
            __builtin_amdgcn_global_load_lds((const GLOBAL_AS void*)ga,
                (LDS_AS void*)(As + half * 2048 + wid * 512), 16, 0, 0);
            __builtin_amdgcn_global_load_lds((const GLOBAL_AS void*)gb,
                (LDS_AS void*)(Bs + half * 2048 + wid * 512), 16, 0, 0);
        }
        __syncthreads();
        int seg = (lane >> 4) * 8;
        int rl = lane & 15;
        short8 a[4], b[4];
        #pragma unroll
        for (int m = 0; m < 4; ++m)
            a[m] = *(const short8*)(As + (wr * 64 + m * 16 + rl) * 32 + seg);
        #pragma unroll
        for (int n = 0; n < 4; ++n)
            b[n] = *(const short8*)(Bs + (wc * 64 + n * 16 + rl) * 32 + seg);
        #pragma unroll
        for (int m = 0; m < 4; ++m)
            #pragma unroll
            for (int n = 0; n < 4; ++n)
                acc[m][n] = __builtin_amdgcn_mfma_f32_16x16x32_bf16(a[m], b[n], acc[m][n], 0, 0, 0);
        __syncthreads();
    }

    float* dst = Mpart + (size_t)kz * 65536;
    int col_l = lane & 15;
    int rseg = (lane >> 4) * 4;
    #pragma unroll
    for (int m = 0; m < 4; ++m) {
        int rbase = m0 + wr * 64 + m * 16 + rseg;
        #pragma unroll
        for (int n = 0; n < 4; ++n) {
            int col = n0 + wc * 64 + n * 16 + col_l;
            #pragma unroll
            for (int j = 0; j < 4; ++j)
                dst[(size_t)(rbase + j) * H_DIM + col] = acc[m][n][j];
        }
    }
}

// ---- Gram finish: Mm = exp(0.4*sum_kz Mpart - 4), rsum[row] = row sum ----
__global__ __launch_bounds__(256) void gram_finish(const float* __restrict__ Mpart,
        float* __restrict__ Mm, float* __restrict__ rsum) {
    __shared__ float red[256];
    int r = blockIdx.x, c = threadIdx.x;
    float s = 0.f;
    #pragma unroll
    for (int kz = 0; kz < 16; ++kz)
        s += Mpart[(size_t)kz * 65536 + (size_t)r * H_DIM + c];
    float e = __expf(0.4f * s - 4.0f);
    Mm[(size_t)r * H_DIM + c] = e;
    red[c] = e;
    __syncthreads();
    #pragma unroll
    for (int st = 128; st > 0; st >>= 1) {
        if (c < st) red[c] += red[c + st];
        __syncthreads();
    }
    if (c == 0) rsum[r] = red[0];
}

// ---- recurrence with warm-up chunks (warm-up 32: 0.5^32 ~ 2e-10 init error) ----
__global__ __launch_bounds__(256) void rec_kernel(const __hip_bfloat16* __restrict__ bmat,
        __hip_bfloat16* __restrict__ cs9b, float* __restrict__ part, float* __restrict__ hxT) {
    int s = blockIdx.x >> 5;
    int b = blockIdx.x & 31;
    int h = threadIdx.x;
    int tout0 = s * 64;
    int t0 = (s == 0) ? 0 : tout0 - 32;
    int t1 = tout0 + 64;
    float c[10] = {};
    float s9 = 0.f;
    float bt[10];
    {
        const __hip_bfloat16* bp = bmat + ((size_t)(t0 * B_DIM + b) * K_DIM) * H_DIM + h;
        #pragma unroll
        for (int k = 0; k < 10; ++k) bt[k] = __bfloat162float(bp[k * H_DIM]);
    }
    for (int t = t0; t < t1; ++t) {
        int tn = (t + 1 < t1) ? t + 1 : t;
        float btn[10];
        const __hip_bfloat16* bq = bmat + ((size_t)(tn * B_DIM + b) * K_DIM) * H_DIM + h;
        #pragma unroll
        for (int k = 0; k < 10; ++k) btn[k] = __bfloat162float(bq[k * H_DIM]);
        #pragma unroll
        for (int j = 9; j >= 1; --j) c[j] = 0.5f * c[j] + c[j - 1] * bt[j];
        c[0] = 0.5f * c[0] + bt[0];
        if (t >= tout0) {
            cs9b[(size_t)(t * B_DIM + b) * H_DIM + h] = __float2bfloat16(c[9]);
            s9 += c[9];
        }
        #pragma unroll
        for (int k = 0; k < 10; ++k) bt[k] = btn[k];
    }
    part[(size_t)(s * B_DIM + b) * H_DIM + h] = s9;
    if (s == 7) {
        float* hp = hxT + (size_t)(b * H_DIM + h) * K_DIM;
        #pragma unroll
        for (int k = 0; k < 10; ++k) hp[k] = c[k];
    }
}

__global__ __launch_bounds__(256) void recred_kernel(const float* __restrict__ part,
        float* __restrict__ mean9) {
    int i = blockIdx.x * 256 + threadIdx.x;            // 0..8191
    float s = 0.f;
    #pragma unroll
    for (int j = 0; j < 8; ++j) s += part[(size_t)j * 8192 + i];
    mean9[i] = s * (1.f / T_DIM);
}

// ---- P1: power iteration (1 block): vbuf = Perron vector, cbuf = {lam, lam-1, rsqrt(lam)-1}
__global__ __launch_bounds__(512) void power_kernel(const float* __restrict__ Mm,
        const float* __restrict__ rsum, float* __restrict__ vbuf, float* __restrict__ cbuf) {
    __shared__ float vv[256];
    __shared__ float yv[256];
    __shared__ float red[512];
    int tid = threadIdx.x;
    if (tid < 256) vv[tid] = rsum[tid];
    __syncthreads();
    for (int it = 0; it <= NPOW; ++it) {
        int col = tid & 255, q = tid >> 8;             // q in {0,1}: 128-row chunks
        const float* mp = Mm + (size_t)q * 128 * 256 + col;
        float p = 0.f;
        #pragma unroll 8
        for (int g = 0; g < 128; ++g) p = fmaf(mp[(size_t)g * 256], vv[q * 128 + g], p);
        red[tid] = p;
        __syncthreads();
        if (it < NPOW) {
            if (tid < 256) {
                float y = red[tid] + red[tid + 256];
                yv[tid] = y;
                red[tid] = y * y;
            }
            __syncthreads();
            #pragma unroll
            for (int st = 128; st > 0; st >>= 1) {
                if (tid < st) red[tid] += red[tid + st];
                __syncthreads();
            }
            float inv = rsqrtf(red[0]);
            if (tid < 256) vv[tid] = yv[tid] * inv;
            __syncthreads();
        } else {
            if (tid < 256) red[tid] = (red[tid] + red[tid + 256]) * vv[tid];  // Rayleigh
            __syncthreads();
            #pragma unroll
            for (int st = 128; st > 0; st >>= 1) {
                if (tid < st) red[tid] += red[tid + st];
                __syncthreads();
            }
            if (tid == 0) {
                float lam = red[0];
                cbuf[0] = lam;
                cbuf[1] = lam - 1.f;
                cbuf[2] = rsqrtf(lam) - 1.f;
            }
        }
    }
    if (tid < 256) vbuf[tid] = vv[tid];
}

// ---- P2: E2 = E @ E, tiled 64x64 over 16 blocks. E rows recomputed from Mm on the fly. ----
__global__ __launch_bounds__(256) void e2_kernel(const float* __restrict__ Mm,
        const float* __restrict__ vbuf, const float* __restrict__ cbuf,
        float* __restrict__ E2g, __hip_bfloat16* __restrict__ e2b) {
    __shared__ __hip_bfloat16 EA[16384];   // [64][256] bf16, row-swizzled
    __shared__ __hip_bfloat16 EC[16384];
    __shared__ float vv[256];
    int tid = threadIdx.x;
    int r0 = (blockIdx.x >> 2) * 64, c0 = (blockIdx.x & 3) * 64;
    float lm1 = cbuf[1];
    if (tid < 256) vv[tid] = vbuf[tid];
    __syncthreads();
    char* pa = (char*)EA;
    char* pc = (char*)EC;
    // stage E rows r0.. and c0.. as bf16 swizzled
    for (int f = tid; f < 4096; f += 256) {
        int row = f >> 6, c4 = (f & 63) << 2;
        {
            int r = r0 + row;
            float4 mv = *(const float4*)(Mm + (size_t)r * 256 + c4);
            float vr = lm1 * vv[r];
            __hip_bfloat16 hb[4];
            hb[0] = __float2bfloat16(mv.x - ((r == c4 + 0) ? 1.f : 0.f) - vr * vv[c4 + 0]);
            hb[1] = __float2bfloat16(mv.y - ((r == c4 + 1) ? 1.f : 0.f) - vr * vv[c4 + 1]);
            hb[2] = __float2bfloat16(mv.z - ((r == c4 + 2) ? 1.f : 0.f) - vr * vv[c4 + 2]);
            hb[3] = __float2bfloat16(mv.w - ((r == c4 + 3) ? 1.f : 0.f) - vr * vv[c4 + 3]);
            *(short4*)(pa + row * 512 + ((c4 * 2) ^ ((row & 7) << 4))) = *(short4*)hb;
        }
        {
            int r = c0 + row;
            float4 mv = *(const float4*)(Mm + (size_t)r * 256 + c4);
            float vr = lm1 * vv[r];
            __hip_bfloat16 hb[4];
            hb[0] = __float2bfloat16(mv.x - ((r == c4 + 0) ? 1.f : 0.f) - vr * vv[c4 + 0]);
            hb[1] = __float2bfloat16(mv.y - ((r == c4 + 1) ? 1.f : 0.f) - vr * vv[c4 + 1]);
            hb[2] = __float2bfloat16(mv.z - ((r == c4 + 2) ? 1.f : 0.f) - vr * vv[c4 + 2]);
            hb[3] = __float2bfloat16(mv.w - ((r == c4 + 3) ? 1.f : 0.f) - vr * vv[c4 + 3]);
            *(short4*)(pc + row * 512 + ((c4 * 2) ^ ((row & 7) << 4))) = *(short4*)hb;
        }
    }
    __syncthreads();
    int wv = tid >> 6, lane = tid & 63;
    int rl = lane & 15, seg8 = (lane >> 4) * 8;
    f32x4 acc[4] = {};
    for (int kb = 0; kb < 256; kb += 32) {
        int row = wv * 16 + rl;
        short8 a = *(const short8*)(pa + row * 512 + (((kb + seg8) * 2) ^ ((rl & 7) << 4)));
        short8 b[4];
        #pragma unroll
        for (int n = 0; n < 4; ++n) {
            int rowb = n * 16 + rl;
            b[n] = *(const short8*)(pc + rowb * 512 + (((kb + seg8) * 2) ^ ((rl & 7) << 4)));
        }
        #pragma unroll
        for (int n = 0; n < 4; ++n)
            acc[n] = __builtin_amdgcn_mfma_f32_16x16x32_bf16(a, b[n], acc[n], 0, 0, 0);
    }
    int col_l = lane & 15, rseg = (lane >> 4) * 4;
    #pragma unroll
    for (int n = 0; n < 4; ++n) {
        #pragma unroll
        for (int j = 0; j < 4; ++j) {
            int r = r0 + wv * 16 + rseg + j;
            int c = c0 + n * 16 + col_l;
            size_t idx = (size_t)r * 256 + c;
            E2g[idx] = acc[n][j];
            e2b[idx] = __float2bfloat16(acc[n][j]);
        }
    }
}

// ---- P3: E3 = E @ E2; fused lin = 1.5I - Mm/2 + (lm1/2+lfac) vv^T + 3/8 E2 - 5/16 E3 ----
__global__ __launch_bounds__(256) void e3lin_kernel(const float* __restrict__ Mm,
        const float* __restrict__ vbuf, const float* __restrict__ cbuf,
        const float* __restrict__ E2g, const __hip_bfloat16* __restrict__ e2b,
        float* __restrict__ lin, __hip_bfloat16* __restrict__ linb) {
    __shared__ __hip_bfloat16 EA[16384];   // [64][256] E rows, swizzled
    __shared__ __hip_bfloat16 EC[16384];   // [64][256] E2 rows (=cols, symmetric), swizzled
    __shared__ float vv[256];
    int tid = threadIdx.x;
    int r0 = (blockIdx.x >> 2) * 64, c0 = (blockIdx.x & 3) * 64;
    float lm1 = cbuf[1];
    float wfac = 0.5f * cbuf[1] + cbuf[2];
    if (tid < 256) vv[tid] = vbuf[tid];
    __syncthreads();
    char* pa = (char*)EA;
    char* pc = (char*)EC;
    for (int f = tid; f < 4096; f += 256) {
        int row = f >> 6, c4 = (f & 63) << 2;
        int r = r0 + row;
        float4 mv = *(const float4*)(Mm + (size_t)r * 256 + c4);
        float vr = lm1 * vv[r];
        __hip_bfloat16 hb[4];
        hb[0] = __float2bfloat16(mv.x - ((r == c4 + 0) ? 1.f : 0.f) - vr * vv[c4 + 0]);
        hb[1] = __float2bfloat16(mv.y - ((r == c4 + 1) ? 1.f : 0.f) - vr * vv[c4 + 1]);
        hb[2] = __float2bfloat16(mv.z - ((r == c4 + 2) ? 1.f : 0.f) - vr * vv[c4 + 2]);
        hb[3] = __float2bfloat16(mv.w - ((r == c4 + 3) ? 1.f : 0.f) - vr * vv[c4 + 3]);
        *(short4*)(pa + row * 512 + ((c4 * 2) ^ ((row & 7) << 4))) = *(short4*)hb;
    }
    for (int f = tid; f < 2048; f += 256) {
        int row = f >> 5, c8 = (f & 31) << 3;
        short8 v8 = *(const short8*)(e2b + (size_t)(c0 + row) * 256 + c8);
        *(short8*)(pc + row * 512 + ((c8 * 2) ^ ((row & 7) << 4))) = v8;
    }
    __syncthreads();
    int wv = tid >> 6, lane = tid & 63;
    int rl = lane & 15, seg8 = (lane >> 4) * 8;
    f32x4 acc[4] = {};
    for (int kb = 0; kb < 256; kb += 32) {
        int row = wv * 16 + rl;
        short8 a = *(const short8*)(pa + row * 512 + (((kb + seg8) * 2) ^ ((rl & 7) << 4)));
        short8 b[4];
        #pragma unroll
        for (int n = 0; n < 4; ++n) {
            int rowb = n * 16 + rl;
            b[n] = *(const short8*)(pc + rowb * 512 + (((kb + seg8) * 2) ^ ((rl & 7) << 4)));
        }
        #pragma unroll
        for (int n = 0; n < 4; ++n)
            acc[n] = __builtin_amdgcn_mfma_f32_16x16x32_bf16(a, b[n], acc[n], 0, 0, 0);
    }
    int col_l = lane & 15, rseg = (lane >> 4) * 4;
    #pragma unroll
    for (int n = 0; n < 4; ++n) {
        #pragma unroll
        for (int j = 0; j < 4; ++j) {
            int r = r0 + wv * 16 + rseg + j;
            int c = c0 + n * 16 + col_l;
            size_t idx = (size_t)r * 256 + c;
            float lv = ((r == c) ? 1.5f : 0.f) - 0.5f * Mm[idx] + wfac * vv[r] * vv[c]
                     + 0.375f * E2g[idx] - 0.3125f * acc[n][j];
            lin[idx] = lv;
            linb[idx] = __float2bfloat16(lv);
        }
    }
}

// ---- out0[b][g] = sum_h mean9[b][h] * lin[h][g] ----
__global__ __launch_bounds__(256) void outmean_kernel(const float* __restrict__ mean9,
        const float* __restrict__ lin, float* __restrict__ out) {
    int b = blockIdx.x, g = threadIdx.x;
    float acc = 0.f;
    const float* mrow = mean9 + b * H_DIM;
    #pragma unroll 8
    for (int h = 0; h < H_DIM; ++h) acc = fmaf(mrow[h], lin[(size_t)h * H_DIM + g], acc);
    out[b * H_DIM + g] = acc;
}

// ---- out1 = cs9b @ linb via bf16 MFMA (lin symmetric -> row-major linb is B^T form) ----
__global__ __launch_bounds__(256) void mm_out1_mfma(const __hip_bfloat16* __restrict__ A,
        const __hip_bfloat16* __restrict__ Bt, float* __restrict__ C) {
    __shared__ __hip_bfloat16 As[4096];   // [128][32]
    __shared__ __hip_bfloat16 Bs[4096];
    int tid = threadIdx.x;
    int wid = tid >> 6, lane = tid & 63;
    int m0 = blockIdx.x * 128, n0 = blockIdx.y * 128;
    int wr = wid >> 1, wc = wid & 1;
    int srow = tid >> 2;
    int scol = (tid & 3) * 8;
    f32x4 acc[4][4] = {};

    for (int kb = 0; kb < 256; kb += 32) {
        #pragma unroll
        for (int half = 0; half < 2; ++half) {
            const __hip_bfloat16* ga = A + (size_t)(m0 + half * 64 + srow) * 256 + kb + scol;
            const __hip_bfloat16* gb = Bt + (size_t)(n0 + half * 64 + srow) * 256 + kb + scol;
            __builtin_amdgcn_global_load_lds((const GLOBAL_AS void*)ga,
                (LDS_AS void*)(As + half * 2048 + wid * 512), 16, 0, 0);
            __builtin_amdgcn_global_load_lds((const GLOBAL_AS void*)gb,
                (LDS_AS void*)(Bs + half * 2048 + wid * 512), 16, 0, 0);
        }
        __syncthreads();
        int seg = (lane >> 4) * 8;
        int rl = lane & 15;
        short8 a[4], b[4];
        #pragma unroll
        for (int m = 0; m < 4; ++m)
            a[m] = *(const short8*)(As + (wr * 64 + m * 16 + rl) * 32 + seg);
        #pragma unroll
        for (int n = 0; n < 4; ++n)
            b[n] = *(const short8*)(Bs + (wc * 64 + n * 16 + rl) * 32 + seg);
        #pragma unroll
        for (int m = 0; m < 4; ++m)
            #pragma unroll
            for (int n = 0; n < 4; ++n)
                acc[m][n] = __builtin_amdgcn_mfma_f32_16x16x32_bf16(a[m], b[n], acc[m][n], 0, 0, 0);
        __syncthreads();
    }

    int col_l = lane & 15;
    int rseg = (lane >> 4) * 4;
    #pragma unroll
    for (int m = 0; m < 4; ++m) {
        int rbase = m0 + wr * 64 + m * 16 + rseg;
        #pragma unroll
        for (int n = 0; n < 4; ++n) {
            int col = n0 + wc * 64 + n * 16 + col_l;
            #pragma unroll
            for (int j = 0; j < 4; ++j)
                C[(size_t)(rbase + j) * 256 + col] = acc[m][n][j];
        }
    }
}

extern "C" void kernel_launch(void* const* d_in, const int* in_sizes, int n_in,
                              void* d_out, int out_size, void* d_ws, size_t ws_size,
                              hipStream_t stream) {
    const float* x = (const float*)d_in[0];
    const float* w = (const float*)d_in[1];
    float* out0 = (float*)d_out;                       // B*H
    float* out1 = out0 + (size_t)B_DIM * H_DIM;        // T*B*H
    float* hxT  = out1 + (size_t)TB * H_DIM;           // B*H*K

    char* ws = (char*)d_ws;
    __hip_bfloat16* wb   = (__hip_bfloat16*)(ws + 0);          // 1,310,720
    __hip_bfloat16* wb2  = (__hip_bfloat16*)(ws + 1310720);    // 1,310,720
    float* xninfo        = (float*)(ws + 2621440);             //   131,072
    float* Mm            = (float*)(ws + 2752512);             //   262,144
    float* rsum          = (float*)(ws + 3014656);             //     1,024
    float* E2g           = (float*)(ws + 3015680);             //   262,144
    __hip_bfloat16* e2b  = (__hip_bfloat16*)(ws + 3277824);    //   131,072
    float* lin           = (float*)(ws + 3408896);             //   262,144
    __hip_bfloat16* linb = (__hip_bfloat16*)(ws + 3671040);    //   131,072
    float* vbuf          = (float*)(ws + 3802112);             //     1,024
    float* cbuf          = (float*)(ws + 3803136);             //     1,024
    float* mean9         = (float*)(ws + 3804160);             //    32,768
    float* part          = (float*)(ws + 3836928);             //   262,144
    __hip_bfloat16* cs9b = (__hip_bfloat16*)(ws + 4099072);    // 8,388,608
    float* Mpart         = (float*)cs9b;                       // 4 MB, aliases cs9b (dead until rec)
    __hip_bfloat16* xb   = (__hip_bfloat16*)(ws + 12487680);   // 8,388,608
    __hip_bfloat16* bmat = (__hip_bfloat16*)(ws + 20876288);   // 83,886,080 -> ~99.9 MB

    wnorm_kernel<<<dim3(640), dim3(256), 0, stream>>>(w, wb, wb2);
    xnorm_kernel<<<dim3(4096), dim3(256), 0, stream>>>(x, xninfo, xb);
    gram_partial<<<dim3(2, 2, 16), dim3(256), 0, stream>>>(wb2, Mpart);
    gram_finish<<<dim3(256), dim3(256), 0, stream>>>(Mpart, Mm, rsum);
    power_kernel<<<dim3(1), dim3(512), 0, stream>>>(Mm, rsum, vbuf, cbuf);
    e2_kernel<<<dim3(16), dim3(256), 0, stream>>>(Mm, vbuf, cbuf, E2g, e2b);
    e3lin_kernel<<<dim3(16), dim3(256), 0, stream>>>(Mm, vbuf, cbuf, E2g, e2b, lin, linb);
    gemm_b_mfma<<<dim3(128, 20), dim3(256), 0, stream>>>(xb, wb, xninfo, bmat);
    rec_kernel<<<dim3(256), dim3(256), 0, stream>>>(bmat, cs9b, part, hxT);
    recred_kernel<<<dim3(32), dim3(256), 0, stream>>>(part, mean9);
    outmean_kernel<<<dim3(32), dim3(256), 0, stream>>>(mean9, lin, out0);
    mm_out1_mfma<<<dim3(128, 2), dim3(256), 0, stream>>>(cs9b, linb, out1);
}